// Round 1
// baseline (1683.869 us; speedup 1.0000x reference)
//
#include <hip/hip_runtime.h>
#include <math.h>

#define NN 20000
#define NE 320000
#define H 256
#define LN_EPS 1e-5f
#define TE 64   // edges per block (edge kernel)
#define TN 32   // nodes per block (node kernel)

__device__ __forceinline__ float silu1(float v) {
    return __fdividef(v, 1.0f + __expf(-v));
}

__device__ __forceinline__ void fma4(float4& a, const float4 w, const float s) {
    a.x = fmaf(w.x, s, a.x);
    a.y = fmaf(w.y, s, a.y);
    a.z = fmaf(w.z, s, a.z);
    a.w = fmaf(w.w, s, a.w);
}

// ---------------- init: zero msg_agg, x_new = x ----------------
__global__ void k_init(const float* __restrict__ x, float* __restrict__ msg,
                       float* __restrict__ xout) {
    const int stride = gridDim.x * blockDim.x;
    const int i0 = blockIdx.x * blockDim.x + threadIdx.x;
    for (int i = i0; i < NN * H; i += stride) msg[i] = 0.0f;
    for (int i = i0; i < NN * 3; i += stride) xout[i] = x[i];
}

// ---------------- pre: P = h @ W_top + b1, Q = h @ W_bot ----------------
// blockIdx.y: 0 -> P, 1 -> Q. 64 nodes per block, 256 threads.
__global__ __launch_bounds__(256) void k_pre(const float* __restrict__ h,
                                             const float* __restrict__ ew1,
                                             const float* __restrict__ eb1,
                                             float* __restrict__ P,
                                             float* __restrict__ Q) {
    __shared__ float At[64][68];   // K-chunk transposed: [k][node]
    const int tid = threadIdx.x;
    const int cg = tid & 63;       // channel group: channels cg*4..+3
    const int ng = tid >> 6;       // node group: nodes ng*16..+15
    const int n0 = blockIdx.x * 64;
    const int which = blockIdx.y;

    float4 acc[16];
    if (which == 0) {
        const float4 b = *(const float4*)(eb1 + cg * 4);
        #pragma unroll
        for (int e = 0; e < 16; e++) acc[e] = b;
    } else {
        #pragma unroll
        for (int e = 0; e < 16; e++) acc[e] = make_float4(0.f, 0.f, 0.f, 0.f);
    }

    const float* wbase = ew1 + (size_t)which * 256 * H + cg * 4;

    for (int kc = 0; kc < 4; kc++) {
        __syncthreads();
        {
            const int kl = (tid & 15) * 4;
            const int ebase = (tid >> 4);
            #pragma unroll
            for (int p = 0; p < 4; p++) {
                const int e = ebase + p * 16;
                int n = n0 + e; n = (n < NN) ? n : 0;
                const float4 v = *(const float4*)(h + (size_t)n * H + kc * 64 + kl);
                At[kl + 0][e] = v.x; At[kl + 1][e] = v.y;
                At[kl + 2][e] = v.z; At[kl + 3][e] = v.w;
            }
        }
        __syncthreads();
        const float* wb = wbase + (size_t)(kc * 64) * H;
        #pragma unroll 2
        for (int k = 0; k < 64; k++) {
            const float4 w = *(const float4*)(wb + (size_t)k * H);
            #pragma unroll
            for (int i = 0; i < 4; i++) {
                const float4 a = *(const float4*)(&At[k][ng * 16 + i * 4]);
                fma4(acc[i * 4 + 0], w, a.x);
                fma4(acc[i * 4 + 1], w, a.y);
                fma4(acc[i * 4 + 2], w, a.z);
                fma4(acc[i * 4 + 3], w, a.w);
            }
        }
    }

    float* out = which ? Q : P;
    #pragma unroll
    for (int e = 0; e < 16; e++) {
        const int n = n0 + ng * 16 + e;
        if (n < NN) *(float4*)(out + (size_t)n * H + cg * 4) = acc[e];
    }
}

// shared GEMM micro-kernel: acc[16 edges][4 ch] += Mt[k][e] * W[k][ch]
__device__ __forceinline__ void gemm_tile(const float* __restrict__ wrow0,
                                          const float (*Mt)[TE + 4], int eg,
                                          float4 acc[16]) {
    #pragma unroll 2
    for (int k = 0; k < H; k++) {
        const float4 w = *(const float4*)(wrow0 + (size_t)k * H);
        #pragma unroll
        for (int i = 0; i < 4; i++) {
            const float4 a = *(const float4*)(&Mt[k][eg * 16 + i * 4]);
            fma4(acc[i * 4 + 0], w, a.x);
            fma4(acc[i * 4 + 1], w, a.y);
            fma4(acc[i * 4 + 2], w, a.z);
            fma4(acc[i * 4 + 3], w, a.w);
        }
    }
}

// ---------------- edge kernel: 64 edges per block, 256 threads ----------------
__global__ __launch_bounds__(256) void k_edge(
    const float* __restrict__ x, const int* __restrict__ ei,
    const float* __restrict__ P, const float* __restrict__ Q,
    const float* __restrict__ ew1,
    const float* __restrict__ ew2, const float* __restrict__ eb2,
    const float* __restrict__ cw1, const float* __restrict__ cb1,
    const float* __restrict__ cw2,
    float* __restrict__ msg, float* __restrict__ xout) {
    __shared__ float Mt[H][TE + 4];   // [channel][edge]: m, then m_ij
    __shared__ float sdiff[TE][4];    // dx,dy,dz,dist_sq
    __shared__ int srow[TE];
    __shared__ int scol[TE];
    __shared__ float scw[TE];

    const int tid = threadIdx.x;
    const int e0 = blockIdx.x * TE;
    const int cg = tid & 63;
    const int eg = tid >> 6;

    if (tid < TE) {
        const int e = e0 + tid;
        const int r = ei[e];
        const int c = ei[NE + e];
        const float dx = x[r * 3 + 0] - x[c * 3 + 0];
        const float dy = x[r * 3 + 1] - x[c * 3 + 1];
        const float dz = x[r * 3 + 2] - x[c * 3 + 2];
        srow[tid] = r; scol[tid] = c;
        sdiff[tid][0] = dx; sdiff[tid][1] = dy; sdiff[tid][2] = dz;
        sdiff[tid][3] = dx * dx + dy * dy + dz * dz;
    }
    __syncthreads();

    // stage m = silu(P[row] + Q[col] + dsq * w_dist) into Mt[ch][e]
    {
        const float wd = ew1[(size_t)512 * H + tid];
        #pragma unroll 4
        for (int e = 0; e < TE; e++) {
            const float v = P[(size_t)srow[e] * H + tid] +
                            Q[(size_t)scol[e] * H + tid] + sdiff[e][3] * wd;
            Mt[tid][e] = silu1(v);
        }
    }
    __syncthreads();

    // GEMM2: m_ij = silu(m @ e_w2 + e_b2)
    float4 acc[16];
    {
        const float4 b2 = *(const float4*)(eb2 + cg * 4);
        #pragma unroll
        for (int e = 0; e < 16; e++) acc[e] = b2;
    }
    gemm_tile(ew2 + cg * 4, (const float (*)[TE + 4])Mt, eg, acc);

    // silu, write m_ij back to Mt (transposed store)
    float sreg[16][4];
    #pragma unroll
    for (int e = 0; e < 16; e++) {
        sreg[e][0] = silu1(acc[e].x); sreg[e][1] = silu1(acc[e].y);
        sreg[e][2] = silu1(acc[e].z); sreg[e][3] = silu1(acc[e].w);
    }
    __syncthreads();   // everyone done reading m
    #pragma unroll
    for (int c = 0; c < 4; c++) {
        #pragma unroll
        for (int i = 0; i < 4; i++) {
            *(float4*)(&Mt[cg * 4 + c][eg * 16 + i * 4]) =
                make_float4(sreg[i * 4 + 0][c], sreg[i * 4 + 1][c],
                            sreg[i * 4 + 2][c], sreg[i * 4 + 3][c]);
        }
    }
    __syncthreads();

    // GEMM3: p = silu(m_ij @ c_w1 + c_b1); coord_weight = p @ c_w2
    {
        const float4 b = *(const float4*)(cb1 + cg * 4);
        #pragma unroll
        for (int e = 0; e < 16; e++) acc[e] = b;
    }
    gemm_tile(cw1 + cg * 4, (const float (*)[TE + 4])Mt, eg, acc);

    {
        const float4 cwv = *(const float4*)(cw2 + cg * 4);
        float part[16];
        #pragma unroll
        for (int e = 0; e < 16; e++) {
            part[e] = silu1(acc[e].x) * cwv.x + silu1(acc[e].y) * cwv.y +
                      silu1(acc[e].z) * cwv.z + silu1(acc[e].w) * cwv.w;
        }
        // butterfly reduce across the 64 lanes (lanes = channel groups)
        #pragma unroll
        for (int m = 1; m < 64; m <<= 1) {
            #pragma unroll
            for (int e = 0; e < 16; e++) part[e] += __shfl_xor(part[e], m);
        }
        #pragma unroll
        for (int i = 0; i < 16; i++)
            if (cg == i) scw[eg * 16 + i] = part[i];
    }
    __syncthreads();

    // coord atomics: x_new[col] += cw * diff
    if (tid < TE) {
        const float cw = scw[tid];
        const int c = scol[tid];
        atomicAdd(xout + (size_t)c * 3 + 0, cw * sdiff[tid][0]);
        atomicAdd(xout + (size_t)c * 3 + 1, cw * sdiff[tid][1]);
        atomicAdd(xout + (size_t)c * 3 + 2, cw * sdiff[tid][2]);
    }

    // msg scatter: msg[col] += m_ij  (Mt still holds m_ij)
    #pragma unroll 2
    for (int e = 0; e < TE; e++) {
        atomicAdd(msg + (size_t)scol[e] * H + tid, Mt[tid][e]);
    }
}

// ---------------- node kernel: 32 nodes per block, 256 threads ----------------
__global__ __launch_bounds__(256) void k_node(
    const float* __restrict__ h, const float* __restrict__ msg,
    const float* __restrict__ nw1, const float* __restrict__ nb1,
    const float* __restrict__ nw2, const float* __restrict__ nb2,
    const float* __restrict__ lng, const float* __restrict__ lnb,
    float* __restrict__ hout) {
    __shared__ float At[64][TN + 4];
    __shared__ float Tt[H][TN + 4];
    const int tid = threadIdx.x;
    const int cg = tid & 63;
    const int ng = tid >> 6;          // nodes ng*8..+7
    const int n0 = blockIdx.x * TN;

    float4 acc[8];
    {
        const float4 b1 = *(const float4*)(nb1 + cg * 4);
        #pragma unroll
        for (int e = 0; e < 8; e++) acc[e] = b1;
    }

    for (int half = 0; half < 2; half++) {
        const float* A = half ? msg : h;
        for (int kc = 0; kc < 4; kc++) {
            __syncthreads();
            {
                const int kl = (tid & 15) * 4;
                const int ebase = (tid >> 4);
                #pragma unroll
                for (int p = 0; p < 2; p++) {
                    const int e = ebase + p * 16;
                    int n = n0 + e; n = (n < NN) ? n : 0;
                    const float4 v = *(const float4*)(A + (size_t)n * H + kc * 64 + kl);
                    At[kl + 0][e] = v.x; At[kl + 1][e] = v.y;
                    At[kl + 2][e] = v.z; At[kl + 3][e] = v.w;
                }
            }
            __syncthreads();
            const float* wb = nw1 + (size_t)(half * 256 + kc * 64) * H + cg * 4;
            #pragma unroll 2
            for (int k = 0; k < 64; k++) {
                const float4 w = *(const float4*)(wb + (size_t)k * H);
                #pragma unroll
                for (int i = 0; i < 2; i++) {
                    const float4 a = *(const float4*)(&At[k][ng * 8 + i * 4]);
                    fma4(acc[i * 4 + 0], w, a.x);
                    fma4(acc[i * 4 + 1], w, a.y);
                    fma4(acc[i * 4 + 2], w, a.z);
                    fma4(acc[i * 4 + 3], w, a.w);
                }
            }
        }
    }

    // t = silu(acc) -> Tt
    {
        float sreg[8][4];
        #pragma unroll
        for (int e = 0; e < 8; e++) {
            sreg[e][0] = silu1(acc[e].x); sreg[e][1] = silu1(acc[e].y);
            sreg[e][2] = silu1(acc[e].z); sreg[e][3] = silu1(acc[e].w);
        }
        __syncthreads();
        #pragma unroll
        for (int c = 0; c < 4; c++) {
            #pragma unroll
            for (int i = 0; i < 2; i++) {
                *(float4*)(&Tt[cg * 4 + c][ng * 8 + i * 4]) =
                    make_float4(sreg[i * 4 + 0][c], sreg[i * 4 + 1][c],
                                sreg[i * 4 + 2][c], sreg[i * 4 + 3][c]);
            }
        }
        __syncthreads();
    }

    // GEMM_B: h_new = t @ n_w2 + n_b2
    float4 y[8];
    {
        const float4 b2 = *(const float4*)(nb2 + cg * 4);
        #pragma unroll
        for (int e = 0; e < 8; e++) y[e] = b2;
    }
    #pragma unroll 2
    for (int k = 0; k < H; k++) {
        const float4 w = *(const float4*)(nw2 + (size_t)k * H + cg * 4);
        #pragma unroll
        for (int i = 0; i < 2; i++) {
            const float4 a = *(const float4*)(&Tt[k][ng * 8 + i * 4]);
            fma4(y[i * 4 + 0], w, a.x);
            fma4(y[i * 4 + 1], w, a.y);
            fma4(y[i * 4 + 2], w, a.z);
            fma4(y[i * 4 + 3], w, a.w);
        }
    }

    // y = h + h_new; LayerNorm over channels
    float s1[8], s2[8];
    #pragma unroll
    for (int e = 0; e < 8; e++) {
        const int n = n0 + ng * 8 + e;
        if (n < NN) {
            const float4 hv = *(const float4*)(h + (size_t)n * H + cg * 4);
            y[e].x += hv.x; y[e].y += hv.y; y[e].z += hv.z; y[e].w += hv.w;
        }
        s1[e] = y[e].x + y[e].y + y[e].z + y[e].w;
        s2[e] = y[e].x * y[e].x + y[e].y * y[e].y + y[e].z * y[e].z + y[e].w * y[e].w;
    }
    #pragma unroll
    for (int m = 1; m < 64; m <<= 1) {
        #pragma unroll
        for (int e = 0; e < 8; e++) {
            s1[e] += __shfl_xor(s1[e], m);
            s2[e] += __shfl_xor(s2[e], m);
        }
    }
    {
        const float4 g = *(const float4*)(lng + cg * 4);
        const float4 bb = *(const float4*)(lnb + cg * 4);
        #pragma unroll
        for (int e = 0; e < 8; e++) {
            const int n = n0 + ng * 8 + e;
            if (n < NN) {
                const float mu = s1[e] * (1.0f / H);
                const float var = s2[e] * (1.0f / H) - mu * mu;
                const float rs = rsqrtf(var + LN_EPS);
                float4 o;
                o.x = (y[e].x - mu) * rs * g.x + bb.x;
                o.y = (y[e].y - mu) * rs * g.y + bb.y;
                o.z = (y[e].z - mu) * rs * g.z + bb.z;
                o.w = (y[e].w - mu) * rs * g.w + bb.w;
                *(float4*)(hout + (size_t)n * H + cg * 4) = o;
            }
        }
    }
}

extern "C" void kernel_launch(void* const* d_in, const int* in_sizes, int n_in,
                              void* d_out, int out_size, void* d_ws, size_t ws_size,
                              hipStream_t stream) {
    const float* h   = (const float*)d_in[0];
    const float* x   = (const float*)d_in[1];
    const int*   ei  = (const int*)d_in[2];
    const float* ew1 = (const float*)d_in[3];
    const float* eb1 = (const float*)d_in[4];
    const float* ew2 = (const float*)d_in[5];
    const float* eb2 = (const float*)d_in[6];
    const float* cw1 = (const float*)d_in[7];
    const float* cb1 = (const float*)d_in[8];
    const float* cw2 = (const float*)d_in[9];
    const float* nw1 = (const float*)d_in[10];
    const float* nb1 = (const float*)d_in[11];
    const float* nw2 = (const float*)d_in[12];
    const float* nb2 = (const float*)d_in[13];
    const float* lng = (const float*)d_in[14];
    const float* lnb = (const float*)d_in[15];

    float* hout = (float*)d_out;
    float* xout = hout + (size_t)NN * H;

    float* msg = (float*)d_ws;
    float* P   = msg + (size_t)NN * H;
    float* Qq  = P + (size_t)NN * H;

    k_init<<<640, 256, 0, stream>>>(x, msg, xout);
    k_pre<<<dim3(313, 2), 256, 0, stream>>>(h, ew1, eb1, P, Qq);
    k_edge<<<NE / TE, 256, 0, stream>>>(x, ei, P, Qq, ew1, ew2, eb2,
                                        cw1, cb1, cw2, msg, xout);
    k_node<<<(NN + TN - 1) / TN, 256, 0, stream>>>(h, msg, nw1, nb1, nw2, nb2,
                                                   lng, lnb, hout);
}

// Round 2
// 843.809 us; speedup vs baseline: 1.9956x; 1.9956x over previous
//
#include <hip/hip_runtime.h>
#include <math.h>

#define NN 20000
#define NE 320000
#define H 256
#define LN_EPS 1e-5f
#define TE 64   // edges per block (edge kernel)
#define TN 32   // nodes per block (node kernel)

typedef _Float16 f16x8 __attribute__((ext_vector_type(8)));
typedef float f32x16 __attribute__((ext_vector_type(16)));

__device__ __forceinline__ float silu1(float v) {
    return __fdividef(v, 1.0f + __expf(-v));
}

__device__ __forceinline__ void fma4(float4& a, const float4 w, const float s) {
    a.x = fmaf(w.x, s, a.x);
    a.y = fmaf(w.y, s, a.y);
    a.z = fmaf(w.z, s, a.z);
    a.w = fmaf(w.w, s, a.w);
}

// ---------------- init: zero msg_agg, x_new = x ----------------
__global__ void k_init(const float* __restrict__ x, float* __restrict__ msg,
                       float* __restrict__ xout) {
    const int stride = gridDim.x * blockDim.x;
    const int i0 = blockIdx.x * blockDim.x + threadIdx.x;
    for (int i = i0; i < NN * H; i += stride) msg[i] = 0.0f;
    for (int i = i0; i < NN * 3; i += stride) xout[i] = x[i];
}

// ---------------- pack weights into B-fragment layout (f16) ----------------
// Bp chunk index = (k>>3)*256 + n ; element j = k&7.
// MFMA B-frag read: lane l, k-step kk, ntile nt: chunk = (kk*2+(l>>5))*256 + n
__global__ void k_pack(const float* __restrict__ ew2, const float* __restrict__ cw1,
                       _Float16* __restrict__ Bp2, _Float16* __restrict__ Bp3) {
    const float* W = blockIdx.y ? cw1 : ew2;
    _Float16* Bp = blockIdx.y ? Bp3 : Bp2;
    const int n = threadIdx.x;
    #pragma unroll
    for (int kr = 0; kr < 4; kr++) {
        const int k = blockIdx.x * 4 + kr;
        Bp[((size_t)(k >> 3) * 256 + n) * 8 + (k & 7)] = (_Float16)W[(size_t)k * 256 + n];
    }
}

// ---------------- pre: P = h @ W_top + b1, Q = h @ W_bot ----------------
__global__ __launch_bounds__(256) void k_pre(const float* __restrict__ h,
                                             const float* __restrict__ ew1,
                                             const float* __restrict__ eb1,
                                             float* __restrict__ P,
                                             float* __restrict__ Q) {
    __shared__ float At[64][68];   // K-chunk transposed: [k][node]
    const int tid = threadIdx.x;
    const int cg = tid & 63;
    const int ng = tid >> 6;
    const int n0 = blockIdx.x * 64;
    const int which = blockIdx.y;

    float4 acc[16];
    if (which == 0) {
        const float4 b = *(const float4*)(eb1 + cg * 4);
        #pragma unroll
        for (int e = 0; e < 16; e++) acc[e] = b;
    } else {
        #pragma unroll
        for (int e = 0; e < 16; e++) acc[e] = make_float4(0.f, 0.f, 0.f, 0.f);
    }

    const float* wbase = ew1 + (size_t)which * 256 * H + cg * 4;

    for (int kc = 0; kc < 4; kc++) {
        __syncthreads();
        {
            const int kl = (tid & 15) * 4;
            const int ebase = (tid >> 4);
            #pragma unroll
            for (int p = 0; p < 4; p++) {
                const int e = ebase + p * 16;
                int n = n0 + e; n = (n < NN) ? n : 0;
                const float4 v = *(const float4*)(h + (size_t)n * H + kc * 64 + kl);
                At[kl + 0][e] = v.x; At[kl + 1][e] = v.y;
                At[kl + 2][e] = v.z; At[kl + 3][e] = v.w;
            }
        }
        __syncthreads();
        const float* wb = wbase + (size_t)(kc * 64) * H;
        #pragma unroll 2
        for (int k = 0; k < 64; k++) {
            const float4 w = *(const float4*)(wb + (size_t)k * H);
            #pragma unroll
            for (int i = 0; i < 4; i++) {
                const float4 a = *(const float4*)(&At[k][ng * 16 + i * 4]);
                fma4(acc[i * 4 + 0], w, a.x);
                fma4(acc[i * 4 + 1], w, a.y);
                fma4(acc[i * 4 + 2], w, a.z);
                fma4(acc[i * 4 + 3], w, a.w);
            }
        }
    }

    float* out = which ? Q : P;
    #pragma unroll
    for (int e = 0; e < 16; e++) {
        const int n = n0 + ng * 16 + e;
        if (n < NN) *(float4*)(out + (size_t)n * H + cg * 4) = acc[e];
    }
}

// ---------------- edge kernel (MFMA): 64 edges per block, 256 threads -------
// LDS A-pack layout: 16B chunks; chunk(kb, e) = kb*64 + (e ^ (kb&7)), kb=c>>3.
__global__ __launch_bounds__(256) void k_edge(
    const float* __restrict__ x, const int* __restrict__ ei,
    const float* __restrict__ P, const float* __restrict__ Q,
    const float* __restrict__ ew1,
    const _Float16* __restrict__ Bp2, const float* __restrict__ eb2,
    const _Float16* __restrict__ Bp3, const float* __restrict__ cb1,
    const float* __restrict__ cw2,
    float* __restrict__ msg, float* __restrict__ xout) {
    __shared__ f16x8 Ap[32 * 64];     // 32 KB: m, then m_ij (A-fragment layout)
    __shared__ float sdiff[TE][4];
    __shared__ int srow[TE];
    __shared__ int scol[TE];
    __shared__ float scw[TE];

    const int tid = threadIdx.x;
    const int e0blk = blockIdx.x * TE;
    const int l = tid & 63;
    const int w = tid >> 6;
    const int l31 = l & 31;
    const int hh = l >> 5;
    const int rb = w >> 1;            // edge row-block (0/1): edges rb*32..+31
    const int chb = (w & 1) * 128;    // channel half: chb..chb+127

    if (tid < TE) {
        const int e = e0blk + tid;
        const int r = ei[e];
        const int c = ei[NE + e];
        const float dx = x[r * 3 + 0] - x[c * 3 + 0];
        const float dy = x[r * 3 + 1] - x[c * 3 + 1];
        const float dz = x[r * 3 + 2] - x[c * 3 + 2];
        srow[tid] = r; scol[tid] = c;
        sdiff[tid][0] = dx; sdiff[tid][1] = dy; sdiff[tid][2] = dz;
        sdiff[tid][3] = dx * dx + dy * dy + dz * dz;
        scw[tid] = 0.0f;
    }
    __syncthreads();

    // ---- stage m = silu(P[row] + Q[col] + dsq*wd) into Ap (f16, A-layout) ----
    {
        const int c8 = (tid & 31) * 8;       // channel octet
        const int kb = tid & 31;             // = c8>>3
        const int eb = tid >> 5;             // base edge 0..7
        const float4 wd0 = *(const float4*)(ew1 + (size_t)512 * H + c8);
        const float4 wd1 = *(const float4*)(ew1 + (size_t)512 * H + c8 + 4);
        #pragma unroll 2
        for (int i = 0; i < 8; i++) {
            const int e = eb + i * 8;
            const int row = srow[e];
            const int col = scol[e];
            const float dsq = sdiff[e][3];
            const float4 p0 = *(const float4*)(P + (size_t)row * H + c8);
            const float4 p1 = *(const float4*)(P + (size_t)row * H + c8 + 4);
            const float4 q0 = *(const float4*)(Q + (size_t)col * H + c8);
            const float4 q1 = *(const float4*)(Q + (size_t)col * H + c8 + 4);
            f16x8 pk;
            pk[0] = (_Float16)silu1(p0.x + q0.x + dsq * wd0.x);
            pk[1] = (_Float16)silu1(p0.y + q0.y + dsq * wd0.y);
            pk[2] = (_Float16)silu1(p0.z + q0.z + dsq * wd0.z);
            pk[3] = (_Float16)silu1(p0.w + q0.w + dsq * wd0.w);
            pk[4] = (_Float16)silu1(p1.x + q1.x + dsq * wd1.x);
            pk[5] = (_Float16)silu1(p1.y + q1.y + dsq * wd1.y);
            pk[6] = (_Float16)silu1(p1.z + q1.z + dsq * wd1.z);
            pk[7] = (_Float16)silu1(p1.w + q1.w + dsq * wd1.w);
            Ap[kb * 64 + (e ^ (kb & 7))] = pk;
        }
    }
    __syncthreads();

    const f16x8* Bp2v = (const f16x8*)Bp2;
    const f16x8* Bp3v = (const f16x8*)Bp3;

    // ---- GEMM2: m_ij = silu(m @ e_w2 + e_b2) ----
    f32x16 acc[4];
    #pragma unroll
    for (int nt = 0; nt < 4; nt++)
        #pragma unroll
        for (int r = 0; r < 16; r++) acc[nt][r] = 0.0f;

    #pragma unroll 4
    for (int kk = 0; kk < 16; kk++) {
        const int kb = kk * 2 + hh;
        const f16x8 a = Ap[kb * 64 + ((rb * 32 + l31) ^ (kb & 7))];
        #pragma unroll
        for (int nt = 0; nt < 4; nt++) {
            const f16x8 b = Bp2v[(size_t)kb * 256 + chb + nt * 32 + l31];
            acc[nt] = __builtin_amdgcn_mfma_f32_32x32x16_f16(a, b, acc[nt], 0, 0, 0);
        }
    }

    // silu + bias in regs
    float mij[4][16];
    #pragma unroll
    for (int nt = 0; nt < 4; nt++) {
        const float bias = eb2[chb + nt * 32 + l31];
        #pragma unroll
        for (int r = 0; r < 16; r++) mij[nt][r] = silu1(acc[nt][r] + bias);
    }

    // msg scatter (coalesced per half-wave): edge e depends on reg, not nt
    {
        int colv[16];
        #pragma unroll
        for (int r = 0; r < 16; r++)
            colv[r] = scol[rb * 32 + (r & 3) + 8 * (r >> 2) + 4 * hh];
        #pragma unroll
        for (int nt = 0; nt < 4; nt++) {
            const int c = chb + nt * 32 + l31;
            #pragma unroll
            for (int r = 0; r < 16; r++)
                atomicAdd(msg + (size_t)colv[r] * H + c, mij[nt][r]);
        }
    }

    __syncthreads();   // all waves done reading m from Ap

    // write m_ij into Ap (A-fragment layout) for GEMM3
    {
        _Float16* Apf = (_Float16*)Ap;
        #pragma unroll
        for (int nt = 0; nt < 4; nt++) {
            const int c = chb + nt * 32 + l31;
            const int kb2 = c >> 3;
            const int j = c & 7;
            #pragma unroll
            for (int r = 0; r < 16; r++) {
                const int e = rb * 32 + (r & 3) + 8 * (r >> 2) + 4 * hh;
                Apf[(size_t)(kb2 * 64 + (e ^ (kb2 & 7))) * 8 + j] = (_Float16)mij[nt][r];
            }
        }
    }
    __syncthreads();

    // ---- GEMM3: p = m_ij @ c_w1 + c_b1; cw = silu(p) . c_w2 ----
    #pragma unroll
    for (int nt = 0; nt < 4; nt++)
        #pragma unroll
        for (int r = 0; r < 16; r++) acc[nt][r] = 0.0f;

    #pragma unroll 4
    for (int kk = 0; kk < 16; kk++) {
        const int kb = kk * 2 + hh;
        const f16x8 a = Ap[kb * 64 + ((rb * 32 + l31) ^ (kb & 7))];
        #pragma unroll
        for (int nt = 0; nt < 4; nt++) {
            const f16x8 b = Bp3v[(size_t)kb * 256 + chb + nt * 32 + l31];
            acc[nt] = __builtin_amdgcn_mfma_f32_32x32x16_f16(a, b, acc[nt], 0, 0, 0);
        }
    }

    {
        float part[16];
        #pragma unroll
        for (int r = 0; r < 16; r++) part[r] = 0.0f;
        #pragma unroll
        for (int nt = 0; nt < 4; nt++) {
            const int c = chb + nt * 32 + l31;
            const float bias = cb1[c];
            const float cwv = cw2[c];
            #pragma unroll
            for (int r = 0; r < 16; r++)
                part[r] += silu1(acc[nt][r] + bias) * cwv;
        }
        #pragma unroll
        for (int m = 1; m < 32; m <<= 1) {
            #pragma unroll
            for (int r = 0; r < 16; r++) part[r] += __shfl_xor(part[r], m);
        }
        if (l31 == 0) {
            #pragma unroll
            for (int r = 0; r < 16; r++) {
                const int e = rb * 32 + (r & 3) + 8 * (r >> 2) + 4 * hh;
                atomicAdd(&scw[e], part[r]);
            }
        }
    }
    __syncthreads();

    // coord atomics: x_new[col] += cw * diff
    if (tid < TE) {
        const float cw = scw[tid];
        const int c = scol[tid];
        atomicAdd(xout + (size_t)c * 3 + 0, cw * sdiff[tid][0]);
        atomicAdd(xout + (size_t)c * 3 + 1, cw * sdiff[tid][1]);
        atomicAdd(xout + (size_t)c * 3 + 2, cw * sdiff[tid][2]);
    }
}

// ---------------- node kernel: 32 nodes per block, 256 threads ----------------
__global__ __launch_bounds__(256) void k_node(
    const float* __restrict__ h, const float* __restrict__ msg,
    const float* __restrict__ nw1, const float* __restrict__ nb1,
    const float* __restrict__ nw2, const float* __restrict__ nb2,
    const float* __restrict__ lng, const float* __restrict__ lnb,
    float* __restrict__ hout) {
    __shared__ float At[64][TN + 4];
    __shared__ float Tt[H][TN + 4];
    const int tid = threadIdx.x;
    const int cg = tid & 63;
    const int ng = tid >> 6;
    const int n0 = blockIdx.x * TN;

    float4 acc[8];
    {
        const float4 b1 = *(const float4*)(nb1 + cg * 4);
        #pragma unroll
        for (int e = 0; e < 8; e++) acc[e] = b1;
    }

    for (int half = 0; half < 2; half++) {
        const float* A = half ? msg : h;
        for (int kc = 0; kc < 4; kc++) {
            __syncthreads();
            {
                const int kl = (tid & 15) * 4;
                const int ebase = (tid >> 4);
                #pragma unroll
                for (int p = 0; p < 2; p++) {
                    const int e = ebase + p * 16;
                    int n = n0 + e; n = (n < NN) ? n : 0;
                    const float4 v = *(const float4*)(A + (size_t)n * H + kc * 64 + kl);
                    At[kl + 0][e] = v.x; At[kl + 1][e] = v.y;
                    At[kl + 2][e] = v.z; At[kl + 3][e] = v.w;
                }
            }
            __syncthreads();
            const float* wb = nw1 + (size_t)(half * 256 + kc * 64) * H + cg * 4;
            #pragma unroll 2
            for (int k = 0; k < 64; k++) {
                const float4 w = *(const float4*)(wb + (size_t)k * H);
                #pragma unroll
                for (int i = 0; i < 2; i++) {
                    const float4 a = *(const float4*)(&At[k][ng * 8 + i * 4]);
                    fma4(acc[i * 4 + 0], w, a.x);
                    fma4(acc[i * 4 + 1], w, a.y);
                    fma4(acc[i * 4 + 2], w, a.z);
                    fma4(acc[i * 4 + 3], w, a.w);
                }
            }
        }
    }

    {
        float sreg[8][4];
        #pragma unroll
        for (int e = 0; e < 8; e++) {
            sreg[e][0] = silu1(acc[e].x); sreg[e][1] = silu1(acc[e].y);
            sreg[e][2] = silu1(acc[e].z); sreg[e][3] = silu1(acc[e].w);
        }
        __syncthreads();
        #pragma unroll
        for (int c = 0; c < 4; c++) {
            #pragma unroll
            for (int i = 0; i < 2; i++) {
                *(float4*)(&Tt[cg * 4 + c][ng * 8 + i * 4]) =
                    make_float4(sreg[i * 4 + 0][c], sreg[i * 4 + 1][c],
                                sreg[i * 4 + 2][c], sreg[i * 4 + 3][c]);
            }
        }
        __syncthreads();
    }

    float4 y[8];
    {
        const float4 b2 = *(const float4*)(nb2 + cg * 4);
        #pragma unroll
        for (int e = 0; e < 8; e++) y[e] = b2;
    }
    #pragma unroll 2
    for (int k = 0; k < H; k++) {
        const float4 w = *(const float4*)(nw2 + (size_t)k * H + cg * 4);
        #pragma unroll
        for (int i = 0; i < 2; i++) {
            const float4 a = *(const float4*)(&Tt[k][ng * 8 + i * 4]);
            fma4(y[i * 4 + 0], w, a.x);
            fma4(y[i * 4 + 1], w, a.y);
            fma4(y[i * 4 + 2], w, a.z);
            fma4(y[i * 4 + 3], w, a.w);
        }
    }

    float s1[8], s2[8];
    #pragma unroll
    for (int e = 0; e < 8; e++) {
        const int n = n0 + ng * 8 + e;
        if (n < NN) {
            const float4 hv = *(const float4*)(h + (size_t)n * H + cg * 4);
            y[e].x += hv.x; y[e].y += hv.y; y[e].z += hv.z; y[e].w += hv.w;
        }
        s1[e] = y[e].x + y[e].y + y[e].z + y[e].w;
        s2[e] = y[e].x * y[e].x + y[e].y * y[e].y + y[e].z * y[e].z + y[e].w * y[e].w;
    }
    #pragma unroll
    for (int m = 1; m < 64; m <<= 1) {
        #pragma unroll
        for (int e = 0; e < 8; e++) {
            s1[e] += __shfl_xor(s1[e], m);
            s2[e] += __shfl_xor(s2[e], m);
        }
    }
    {
        const float4 g = *(const float4*)(lng + cg * 4);
        const float4 bb = *(const float4*)(lnb + cg * 4);
        #pragma unroll
        for (int e = 0; e < 8; e++) {
            const int n = n0 + ng * 8 + e;
            if (n < NN) {
                const float mu = s1[e] * (1.0f / H);
                const float var = s2[e] * (1.0f / H) - mu * mu;
                const float rs = rsqrtf(var + LN_EPS);
                float4 o;
                o.x = (y[e].x - mu) * rs * g.x + bb.x;
                o.y = (y[e].y - mu) * rs * g.y + bb.y;
                o.z = (y[e].z - mu) * rs * g.z + bb.z;
                o.w = (y[e].w - mu) * rs * g.w + bb.w;
                *(float4*)(hout + (size_t)n * H + cg * 4) = o;
            }
        }
    }
}

extern "C" void kernel_launch(void* const* d_in, const int* in_sizes, int n_in,
                              void* d_out, int out_size, void* d_ws, size_t ws_size,
                              hipStream_t stream) {
    const float* h   = (const float*)d_in[0];
    const float* x   = (const float*)d_in[1];
    const int*   ei  = (const int*)d_in[2];
    const float* ew1 = (const float*)d_in[3];
    const float* eb1 = (const float*)d_in[4];
    const float* ew2 = (const float*)d_in[5];
    const float* eb2 = (const float*)d_in[6];
    const float* cw1 = (const float*)d_in[7];
    const float* cb1 = (const float*)d_in[8];
    const float* cw2 = (const float*)d_in[9];
    const float* nw1 = (const float*)d_in[10];
    const float* nb1 = (const float*)d_in[11];
    const float* nw2 = (const float*)d_in[12];
    const float* nb2 = (const float*)d_in[13];
    const float* lng = (const float*)d_in[14];
    const float* lnb = (const float*)d_in[15];

    float* hout = (float*)d_out;
    float* xout = hout + (size_t)NN * H;

    float* msg = (float*)d_ws;
    float* P   = msg + (size_t)NN * H;
    float* Qq  = P + (size_t)NN * H;
    _Float16* Bp2 = (_Float16*)(Qq + (size_t)NN * H);
    _Float16* Bp3 = Bp2 + (size_t)H * H;

    k_init<<<640, 256, 0, stream>>>(x, msg, xout);
    k_pack<<<dim3(64, 2), 256, 0, stream>>>(ew2, cw1, Bp2, Bp3);
    k_pre<<<dim3(313, 2), 256, 0, stream>>>(h, ew1, eb1, P, Qq);
    k_edge<<<NE / TE, 256, 0, stream>>>(x, ei, P, Qq, ew1, Bp2, eb2,
                                        Bp3, cb1, cw2, msg, xout);
    k_node<<<(NN + TN - 1) / TN, 256, 0, stream>>>(h, msg, nw1, nb1, nw2, nb2,
                                                   lng, lnb, hout);
}

// Round 3
// 778.789 us; speedup vs baseline: 2.1622x; 1.0835x over previous
//
#include <hip/hip_runtime.h>
#include <math.h>

#define NN 20000
#define NE 320000
#define H 256
#define LN_EPS 1e-5f
#define TE 64   // edges per block (edge kernel)
#define TN 32   // nodes per block (node kernel)

typedef _Float16 f16x8 __attribute__((ext_vector_type(8)));
typedef float f32x16 __attribute__((ext_vector_type(16)));

__device__ __forceinline__ float silu1(float v) {
    return __fdividef(v, 1.0f + __expf(-v));
}

__device__ __forceinline__ void fma4(float4& a, const float4 w, const float s) {
    a.x = fmaf(w.x, s, a.x);
    a.y = fmaf(w.y, s, a.y);
    a.z = fmaf(w.z, s, a.z);
    a.w = fmaf(w.w, s, a.w);
}

// ---------------- init: zero msg_agg + hist bins, x_new = x ----------------
__global__ void k_init(const float* __restrict__ x, float* __restrict__ msg,
                       float* __restrict__ xout, int* __restrict__ bins) {
    const int stride = gridDim.x * blockDim.x;
    const int i0 = blockIdx.x * blockDim.x + threadIdx.x;
    for (int i = i0; i < NN * H; i += stride) msg[i] = 0.0f;
    for (int i = i0; i < NN * 3; i += stride) xout[i] = x[i];
    for (int i = i0; i < NN; i += stride) bins[i] = 0;
}

// ---------------- counting sort by col ----------------
__global__ void k_hist(const int* __restrict__ ei, int* __restrict__ bins) {
    const int e = blockIdx.x * blockDim.x + threadIdx.x;
    if (e < NE) atomicAdd(&bins[ei[NE + e]], 1);
}

__global__ __launch_bounds__(1024) void k_scan(const int* __restrict__ bins,
                                               int* __restrict__ cursor) {
    __shared__ int s[1024];
    const int tid = threadIdx.x;
    const int base = tid * 20;        // 1024*20 = 20480 >= 20000
    int loc[20];
    int sum = 0;
    #pragma unroll
    for (int j = 0; j < 20; j++) {
        const int idx = base + j;
        const int v = (idx < NN) ? bins[idx] : 0;
        loc[j] = sum;                 // exclusive within chunk
        sum += v;
    }
    s[tid] = sum;
    __syncthreads();
    for (int off = 1; off < 1024; off <<= 1) {
        const int v = (tid >= off) ? s[tid - off] : 0;
        __syncthreads();
        s[tid] += v;
        __syncthreads();
    }
    const int excl = s[tid] - sum;
    #pragma unroll
    for (int j = 0; j < 20; j++) {
        const int idx = base + j;
        if (idx < NN) cursor[idx] = excl + loc[j];
    }
}

__global__ void k_scatter(const int* __restrict__ ei, int* __restrict__ cursor,
                          int* __restrict__ perm) {
    const int e = blockIdx.x * blockDim.x + threadIdx.x;
    if (e < NE) {
        const int c = ei[NE + e];
        const int pos = atomicAdd(&cursor[c], 1);
        perm[pos] = e;
    }
}

// ---------------- pack weights into B-fragment layout (f16) ----------------
__global__ void k_pack(const float* __restrict__ ew2, const float* __restrict__ cw1,
                       _Float16* __restrict__ Bp2, _Float16* __restrict__ Bp3) {
    const float* W = blockIdx.y ? cw1 : ew2;
    _Float16* Bp = blockIdx.y ? Bp3 : Bp2;
    const int n = threadIdx.x;
    #pragma unroll
    for (int kr = 0; kr < 4; kr++) {
        const int k = blockIdx.x * 4 + kr;
        Bp[((size_t)(k >> 3) * 256 + n) * 8 + (k & 7)] = (_Float16)W[(size_t)k * 256 + n];
    }
}

// ---------------- pre: P = h @ W_top + b1, Q = h @ W_bot ----------------
__global__ __launch_bounds__(256) void k_pre(const float* __restrict__ h,
                                             const float* __restrict__ ew1,
                                             const float* __restrict__ eb1,
                                             float* __restrict__ P,
                                             float* __restrict__ Q) {
    __shared__ float At[64][68];
    const int tid = threadIdx.x;
    const int cg = tid & 63;
    const int ng = tid >> 6;
    const int n0 = blockIdx.x * 64;
    const int which = blockIdx.y;

    float4 acc[16];
    if (which == 0) {
        const float4 b = *(const float4*)(eb1 + cg * 4);
        #pragma unroll
        for (int e = 0; e < 16; e++) acc[e] = b;
    } else {
        #pragma unroll
        for (int e = 0; e < 16; e++) acc[e] = make_float4(0.f, 0.f, 0.f, 0.f);
    }

    const float* wbase = ew1 + (size_t)which * 256 * H + cg * 4;

    for (int kc = 0; kc < 4; kc++) {
        __syncthreads();
        {
            const int kl = (tid & 15) * 4;
            const int ebase = (tid >> 4);
            #pragma unroll
            for (int p = 0; p < 4; p++) {
                const int e = ebase + p * 16;
                int n = n0 + e; n = (n < NN) ? n : 0;
                const float4 v = *(const float4*)(h + (size_t)n * H + kc * 64 + kl);
                At[kl + 0][e] = v.x; At[kl + 1][e] = v.y;
                At[kl + 2][e] = v.z; At[kl + 3][e] = v.w;
            }
        }
        __syncthreads();
        const float* wb = wbase + (size_t)(kc * 64) * H;
        #pragma unroll 2
        for (int k = 0; k < 64; k++) {
            const float4 w = *(const float4*)(wb + (size_t)k * H);
            #pragma unroll
            for (int i = 0; i < 4; i++) {
                const float4 a = *(const float4*)(&At[k][ng * 16 + i * 4]);
                fma4(acc[i * 4 + 0], w, a.x);
                fma4(acc[i * 4 + 1], w, a.y);
                fma4(acc[i * 4 + 2], w, a.z);
                fma4(acc[i * 4 + 3], w, a.w);
            }
        }
    }

    float* out = which ? Q : P;
    #pragma unroll
    for (int e = 0; e < 16; e++) {
        const int n = n0 + ng * 16 + e;
        if (n < NN) *(float4*)(out + (size_t)n * H + cg * 4) = acc[e];
    }
}

// ---------------- edge kernel (MFMA, col-sorted edges) ----------------
// LDS A-pack layout: 16B chunks; chunk(kb, e) = kb*64 + (e ^ (kb&7)), kb=c>>3.
__global__ __launch_bounds__(256) void k_edge(
    const float* __restrict__ x, const int* __restrict__ ei,
    const int* __restrict__ perm,
    const float* __restrict__ P, const float* __restrict__ Q,
    const float* __restrict__ ew1,
    const _Float16* __restrict__ Bp2, const float* __restrict__ eb2,
    const _Float16* __restrict__ Bp3, const float* __restrict__ cb1,
    const float* __restrict__ cw2,
    float* __restrict__ msg, float* __restrict__ xout) {
    __shared__ f16x8 Ap[32 * 64];     // 32 KB: m, then m_ij (A-fragment layout)
    __shared__ float sdiff[TE][4];
    __shared__ int srow[TE];
    __shared__ int scol[TE];
    __shared__ float scw[TE];

    const int tid = threadIdx.x;
    const int e0blk = blockIdx.x * TE;
    const int l = tid & 63;
    const int w = tid >> 6;
    const int l31 = l & 31;
    const int hh = l >> 5;
    const int rb = w >> 1;            // edge row-block (0/1)
    const int chb = (w & 1) * 128;    // channel half

    if (tid < TE) {
        const int e = perm[e0blk + tid];
        const int r = ei[e];
        const int c = ei[NE + e];
        const float dx = x[r * 3 + 0] - x[c * 3 + 0];
        const float dy = x[r * 3 + 1] - x[c * 3 + 1];
        const float dz = x[r * 3 + 2] - x[c * 3 + 2];
        srow[tid] = r; scol[tid] = c;
        sdiff[tid][0] = dx; sdiff[tid][1] = dy; sdiff[tid][2] = dz;
        sdiff[tid][3] = dx * dx + dy * dy + dz * dz;
        scw[tid] = 0.0f;
    }
    __syncthreads();

    // ---- stage m = silu(P[row] + Q[col] + dsq*wd) into Ap (f16, A-layout) ----
    {
        const int c8 = (tid & 31) * 8;
        const int kb = tid & 31;
        const int eb = tid >> 5;
        const float4 wd0 = *(const float4*)(ew1 + (size_t)512 * H + c8);
        const float4 wd1 = *(const float4*)(ew1 + (size_t)512 * H + c8 + 4);
        #pragma unroll 2
        for (int i = 0; i < 8; i++) {
            const int e = eb + i * 8;
            const int row = srow[e];
            const int col = scol[e];
            const float dsq = sdiff[e][3];
            const float4 p0 = *(const float4*)(P + (size_t)row * H + c8);
            const float4 p1 = *(const float4*)(P + (size_t)row * H + c8 + 4);
            const float4 q0 = *(const float4*)(Q + (size_t)col * H + c8);
            const float4 q1 = *(const float4*)(Q + (size_t)col * H + c8 + 4);
            f16x8 pk;
            pk[0] = (_Float16)silu1(p0.x + q0.x + dsq * wd0.x);
            pk[1] = (_Float16)silu1(p0.y + q0.y + dsq * wd0.y);
            pk[2] = (_Float16)silu1(p0.z + q0.z + dsq * wd0.z);
            pk[3] = (_Float16)silu1(p0.w + q0.w + dsq * wd0.w);
            pk[4] = (_Float16)silu1(p1.x + q1.x + dsq * wd1.x);
            pk[5] = (_Float16)silu1(p1.y + q1.y + dsq * wd1.y);
            pk[6] = (_Float16)silu1(p1.z + q1.z + dsq * wd1.z);
            pk[7] = (_Float16)silu1(p1.w + q1.w + dsq * wd1.w);
            Ap[kb * 64 + (e ^ (kb & 7))] = pk;
        }
    }
    __syncthreads();

    const f16x8* Bp2v = (const f16x8*)Bp2;
    const f16x8* Bp3v = (const f16x8*)Bp3;

    // ---- GEMM2: m_ij = silu(m @ e_w2 + e_b2) ----
    f32x16 acc[4];
    #pragma unroll
    for (int nt = 0; nt < 4; nt++)
        #pragma unroll
        for (int r = 0; r < 16; r++) acc[nt][r] = 0.0f;

    #pragma unroll 4
    for (int kk = 0; kk < 16; kk++) {
        const int kb = kk * 2 + hh;
        const f16x8 a = Ap[kb * 64 + ((rb * 32 + l31) ^ (kb & 7))];
        #pragma unroll
        for (int nt = 0; nt < 4; nt++) {
            const f16x8 b = Bp2v[(size_t)kb * 256 + chb + nt * 32 + l31];
            acc[nt] = __builtin_amdgcn_mfma_f32_32x32x16_f16(a, b, acc[nt], 0, 0, 0);
        }
    }

    // silu + bias in regs
    float mij[4][16];
    #pragma unroll
    for (int nt = 0; nt < 4; nt++) {
        const float bias = eb2[chb + nt * 32 + l31];
        #pragma unroll
        for (int r = 0; r < 16; r++) mij[nt][r] = silu1(acc[nt][r] + bias);
    }

    __syncthreads();   // all waves done reading m from Ap

    // write m_ij into Ap (A-fragment layout) for GEMM3 + segmented reduction
    {
        _Float16* Apf = (_Float16*)Ap;
        #pragma unroll
        for (int nt = 0; nt < 4; nt++) {
            const int c = chb + nt * 32 + l31;
            const int kb2 = c >> 3;
            const int j = c & 7;
            #pragma unroll
            for (int r = 0; r < 16; r++) {
                const int e = rb * 32 + (r & 3) + 8 * (r >> 2) + 4 * hh;
                Apf[(size_t)(kb2 * 64 + (e ^ (kb2 & 7))) * 8 + j] = (_Float16)mij[nt][r];
            }
        }
    }
    __syncthreads();

    // ---- GEMM3: p = m_ij @ c_w1 + c_b1; cw = silu(p) . c_w2 ----
    #pragma unroll
    for (int nt = 0; nt < 4; nt++)
        #pragma unroll
        for (int r = 0; r < 16; r++) acc[nt][r] = 0.0f;

    #pragma unroll 4
    for (int kk = 0; kk < 16; kk++) {
        const int kb = kk * 2 + hh;
        const f16x8 a = Ap[kb * 64 + ((rb * 32 + l31) ^ (kb & 7))];
        #pragma unroll
        for (int nt = 0; nt < 4; nt++) {
            const f16x8 b = Bp3v[(size_t)kb * 256 + chb + nt * 32 + l31];
            acc[nt] = __builtin_amdgcn_mfma_f32_32x32x16_f16(a, b, acc[nt], 0, 0, 0);
        }
    }

    {
        float part[16];
        #pragma unroll
        for (int r = 0; r < 16; r++) part[r] = 0.0f;
        #pragma unroll
        for (int nt = 0; nt < 4; nt++) {
            const int c = chb + nt * 32 + l31;
            const float bias = cb1[c];
            const float cwv = cw2[c];
            #pragma unroll
            for (int r = 0; r < 16; r++)
                part[r] += silu1(acc[nt][r] + bias) * cwv;
        }
        #pragma unroll
        for (int m = 1; m < 32; m <<= 1) {
            #pragma unroll
            for (int r = 0; r < 16; r++) part[r] += __shfl_xor(part[r], m);
        }
        if (l31 == 0) {
            #pragma unroll
            for (int r = 0; r < 16; r++) {
                const int e = rb * 32 + (r & 3) + 8 * (r >> 2) + 4 * hh;
                atomicAdd(&scw[e], part[r]);
            }
        }
    }

    // ---- msg segmented reduction: cols sorted within block ----
    // thread tid owns channel c = tid; m_ij is in Ap (A-frag layout).
    // col-change branch is wave-uniform (all lanes share e).
    {
        const _Float16* Apf = (const _Float16*)Ap;
        const int kb = tid >> 3;
        const int j = tid & 7;
        float accm = 0.0f;
        #pragma unroll 4
        for (int e = 0; e < TE; e++) {
            accm += (float)Apf[(size_t)(kb * 64 + (e ^ (kb & 7))) * 8 + j];
            const int col = scol[e];
            const int nxt = (e == TE - 1) ? -1 : scol[e + 1];
            if (col != nxt) {
                atomicAdd(msg + (size_t)col * H + tid, accm);
                accm = 0.0f;
            }
        }
    }
    __syncthreads();   // scw complete

    // ---- coord segmented reduction: x_new[col] += cw * diff ----
    if (tid < 3) {
        const int d = tid;
        float accc = 0.0f;
        for (int e = 0; e < TE; e++) {
            accc += scw[e] * sdiff[e][d];
            const int col = scol[e];
            const int nxt = (e == TE - 1) ? -1 : scol[e + 1];
            if (col != nxt) {
                atomicAdd(xout + (size_t)col * 3 + d, accc);
                accc = 0.0f;
            }
        }
    }
}

// ---------------- node kernel: 32 nodes per block, 256 threads ----------------
__global__ __launch_bounds__(256) void k_node(
    const float* __restrict__ h, const float* __restrict__ msg,
    const float* __restrict__ nw1, const float* __restrict__ nb1,
    const float* __restrict__ nw2, const float* __restrict__ nb2,
    const float* __restrict__ lng, const float* __restrict__ lnb,
    float* __restrict__ hout) {
    __shared__ float At[64][TN + 4];
    __shared__ float Tt[H][TN + 4];
    const int tid = threadIdx.x;
    const int cg = tid & 63;
    const int ng = tid >> 6;
    const int n0 = blockIdx.x * TN;

    float4 acc[8];
    {
        const float4 b1 = *(const float4*)(nb1 + cg * 4);
        #pragma unroll
        for (int e = 0; e < 8; e++) acc[e] = b1;
    }

    for (int half = 0; half < 2; half++) {
        const float* A = half ? msg : h;
        for (int kc = 0; kc < 4; kc++) {
            __syncthreads();
            {
                const int kl = (tid & 15) * 4;
                const int ebase = (tid >> 4);
                #pragma unroll
                for (int p = 0; p < 2; p++) {
                    const int e = ebase + p * 16;
                    int n = n0 + e; n = (n < NN) ? n : 0;
                    const float4 v = *(const float4*)(A + (size_t)n * H + kc * 64 + kl);
                    At[kl + 0][e] = v.x; At[kl + 1][e] = v.y;
                    At[kl + 2][e] = v.z; At[kl + 3][e] = v.w;
                }
            }
            __syncthreads();
            const float* wb = nw1 + (size_t)(half * 256 + kc * 64) * H + cg * 4;
            #pragma unroll 2
            for (int k = 0; k < 64; k++) {
                const float4 w = *(const float4*)(wb + (size_t)k * H);
                #pragma unroll
                for (int i = 0; i < 2; i++) {
                    const float4 a = *(const float4*)(&At[k][ng * 8 + i * 4]);
                    fma4(acc[i * 4 + 0], w, a.x);
                    fma4(acc[i * 4 + 1], w, a.y);
                    fma4(acc[i * 4 + 2], w, a.z);
                    fma4(acc[i * 4 + 3], w, a.w);
                }
            }
        }
    }

    {
        float sreg[8][4];
        #pragma unroll
        for (int e = 0; e < 8; e++) {
            sreg[e][0] = silu1(acc[e].x); sreg[e][1] = silu1(acc[e].y);
            sreg[e][2] = silu1(acc[e].z); sreg[e][3] = silu1(acc[e].w);
        }
        __syncthreads();
        #pragma unroll
        for (int c = 0; c < 4; c++) {
            #pragma unroll
            for (int i = 0; i < 2; i++) {
                *(float4*)(&Tt[cg * 4 + c][ng * 8 + i * 4]) =
                    make_float4(sreg[i * 4 + 0][c], sreg[i * 4 + 1][c],
                                sreg[i * 4 + 2][c], sreg[i * 4 + 3][c]);
            }
        }
        __syncthreads();
    }

    float4 y[8];
    {
        const float4 b2 = *(const float4*)(nb2 + cg * 4);
        #pragma unroll
        for (int e = 0; e < 8; e++) y[e] = b2;
    }
    #pragma unroll 2
    for (int k = 0; k < H; k++) {
        const float4 w = *(const float4*)(nw2 + (size_t)k * H + cg * 4);
        #pragma unroll
        for (int i = 0; i < 2; i++) {
            const float4 a = *(const float4*)(&Tt[k][ng * 8 + i * 4]);
            fma4(y[i * 4 + 0], w, a.x);
            fma4(y[i * 4 + 1], w, a.y);
            fma4(y[i * 4 + 2], w, a.z);
            fma4(y[i * 4 + 3], w, a.w);
        }
    }

    float s1[8], s2[8];
    #pragma unroll
    for (int e = 0; e < 8; e++) {
        const int n = n0 + ng * 8 + e;
        if (n < NN) {
            const float4 hv = *(const float4*)(h + (size_t)n * H + cg * 4);
            y[e].x += hv.x; y[e].y += hv.y; y[e].z += hv.z; y[e].w += hv.w;
        }
        s1[e] = y[e].x + y[e].y + y[e].z + y[e].w;
        s2[e] = y[e].x * y[e].x + y[e].y * y[e].y + y[e].z * y[e].z + y[e].w * y[e].w;
    }
    #pragma unroll
    for (int m = 1; m < 64; m <<= 1) {
        #pragma unroll
        for (int e = 0; e < 8; e++) {
            s1[e] += __shfl_xor(s1[e], m);
            s2[e] += __shfl_xor(s2[e], m);
        }
    }
    {
        const float4 g = *(const float4*)(lng + cg * 4);
        const float4 bb = *(const float4*)(lnb + cg * 4);
        #pragma unroll
        for (int e = 0; e < 8; e++) {
            const int n = n0 + ng * 8 + e;
            if (n < NN) {
                const float mu = s1[e] * (1.0f / H);
                const float var = s2[e] * (1.0f / H) - mu * mu;
                const float rs = rsqrtf(var + LN_EPS);
                float4 o;
                o.x = (y[e].x - mu) * rs * g.x + bb.x;
                o.y = (y[e].y - mu) * rs * g.y + bb.y;
                o.z = (y[e].z - mu) * rs * g.z + bb.z;
                o.w = (y[e].w - mu) * rs * g.w + bb.w;
                *(float4*)(hout + (size_t)n * H + cg * 4) = o;
            }
        }
    }
}

extern "C" void kernel_launch(void* const* d_in, const int* in_sizes, int n_in,
                              void* d_out, int out_size, void* d_ws, size_t ws_size,
                              hipStream_t stream) {
    const float* h   = (const float*)d_in[0];
    const float* x   = (const float*)d_in[1];
    const int*   ei  = (const int*)d_in[2];
    const float* ew1 = (const float*)d_in[3];
    const float* eb1 = (const float*)d_in[4];
    const float* ew2 = (const float*)d_in[5];
    const float* eb2 = (const float*)d_in[6];
    const float* cw1 = (const float*)d_in[7];
    const float* cb1 = (const float*)d_in[8];
    const float* cw2 = (const float*)d_in[9];
    const float* nw1 = (const float*)d_in[10];
    const float* nb1 = (const float*)d_in[11];
    const float* nw2 = (const float*)d_in[12];
    const float* nb2 = (const float*)d_in[13];
    const float* lng = (const float*)d_in[14];
    const float* lnb = (const float*)d_in[15];

    float* hout = (float*)d_out;
    float* xout = hout + (size_t)NN * H;

    float* msg = (float*)d_ws;
    float* P   = msg + (size_t)NN * H;
    float* Qq  = P + (size_t)NN * H;
    _Float16* Bp2 = (_Float16*)(Qq + (size_t)NN * H);
    _Float16* Bp3 = Bp2 + (size_t)H * H;
    int* bins   = (int*)(Bp3 + (size_t)H * H);
    int* cursor = bins + NN;
    int* perm   = cursor + NN;

    k_init<<<640, 256, 0, stream>>>(x, msg, xout, bins);
    k_hist<<<(NE + 255) / 256, 256, 0, stream>>>(ei, bins);
    k_scan<<<1, 1024, 0, stream>>>(bins, cursor);
    k_scatter<<<(NE + 255) / 256, 256, 0, stream>>>(ei, cursor, perm);
    k_pack<<<dim3(64, 2), 256, 0, stream>>>(ew2, cw1, Bp2, Bp3);
    k_pre<<<dim3(313, 2), 256, 0, stream>>>(h, ew1, eb1, P, Qq);
    k_edge<<<NE / TE, 256, 0, stream>>>(x, ei, perm, P, Qq, ew1, Bp2, eb2,
                                        Bp3, cb1, cw2, msg, xout);
    k_node<<<(NN + TN - 1) / TN, 256, 0, stream>>>(h, msg, nw1, nb1, nw2, nb2,
                                                   lng, lnb, hout);
}

// Round 4
// 527.945 us; speedup vs baseline: 3.1895x; 1.4751x over previous
//
#include <hip/hip_runtime.h>
#include <math.h>

#define NN 20000
#define NE 320000
#define H 256
#define LN_EPS 1e-5f
#define TE 64   // edges per block (edge kernel)

typedef _Float16 f16x8 __attribute__((ext_vector_type(8)));
typedef float f32x16 __attribute__((ext_vector_type(16)));

__device__ __forceinline__ float silu1(float v) {
    return __fdividef(v, 1.0f + __expf(-v));
}

// ---------------- init: zero msg_agg + hist bins, x_new = x ----------------
__global__ void k_init(const float* __restrict__ x, float* __restrict__ msg,
                       float* __restrict__ xout, int* __restrict__ bins) {
    const int stride = gridDim.x * blockDim.x;
    const int i0 = blockIdx.x * blockDim.x + threadIdx.x;
    for (int i = i0; i < NN * H; i += stride) msg[i] = 0.0f;
    for (int i = i0; i < NN * 3; i += stride) xout[i] = x[i];
    for (int i = i0; i < NN; i += stride) bins[i] = 0;
}

// ---------------- counting sort by col ----------------
__global__ void k_hist(const int* __restrict__ ei, int* __restrict__ bins) {
    const int e = blockIdx.x * blockDim.x + threadIdx.x;
    if (e < NE) atomicAdd(&bins[ei[NE + e]], 1);
}

__global__ __launch_bounds__(1024) void k_scan(const int* __restrict__ bins,
                                               int* __restrict__ cursor) {
    __shared__ int s[1024];
    const int tid = threadIdx.x;
    const int base = tid * 20;
    int loc[20];
    int sum = 0;
    #pragma unroll
    for (int j = 0; j < 20; j++) {
        const int idx = base + j;
        const int v = (idx < NN) ? bins[idx] : 0;
        loc[j] = sum;
        sum += v;
    }
    s[tid] = sum;
    __syncthreads();
    for (int off = 1; off < 1024; off <<= 1) {
        const int v = (tid >= off) ? s[tid - off] : 0;
        __syncthreads();
        s[tid] += v;
        __syncthreads();
    }
    const int excl = s[tid] - sum;
    #pragma unroll
    for (int j = 0; j < 20; j++) {
        const int idx = base + j;
        if (idx < NN) cursor[idx] = excl + loc[j];
    }
}

__global__ void k_scatter(const int* __restrict__ ei, int* __restrict__ cursor,
                          int* __restrict__ perm) {
    const int e = blockIdx.x * blockDim.x + threadIdx.x;
    if (e < NE) {
        const int c = ei[NE + e];
        const int pos = atomicAdd(&cursor[c], 1);
        perm[pos] = e;
    }
}

// ---------------- pack all weights into B-fragment layout (f16) -------------
// Bp chunk index = (k>>3)*N + n ; element j = k&7.
__global__ void k_pack(const float* __restrict__ ew2, const float* __restrict__ cw1,
                       const float* __restrict__ nw2, const float* __restrict__ nw1,
                       const float* __restrict__ ew1,
                       _Float16* __restrict__ Bp2, _Float16* __restrict__ Bp3,
                       _Float16* __restrict__ BpB, _Float16* __restrict__ BpA,
                       _Float16* __restrict__ Bp1) {
    const int which = blockIdx.y;
    const int n = threadIdx.x;
    if (which < 3) {                       // K=256, N=256
        if (blockIdx.x >= 64) return;
        const float* W = (which == 0) ? ew2 : (which == 1) ? cw1 : nw2;
        _Float16* Bp = (which == 0) ? Bp2 : (which == 1) ? Bp3 : BpB;
        #pragma unroll
        for (int kr = 0; kr < 4; kr++) {
            const int k = blockIdx.x * 4 + kr;
            Bp[((size_t)(k >> 3) * 256 + n) * 8 + (k & 7)] =
                (_Float16)W[(size_t)k * 256 + n];
        }
    } else if (which == 3) {               // nw1: K=512, N=256
        #pragma unroll
        for (int kr = 0; kr < 4; kr++) {
            const int k = blockIdx.x * 4 + kr;
            BpA[((size_t)(k >> 3) * 256 + n) * 8 + (k & 7)] =
                (_Float16)nw1[(size_t)k * 256 + n];
        }
    } else {                               // ew1 combined: K=256, N=512
        if (blockIdx.x >= 64) return;
        #pragma unroll
        for (int kr = 0; kr < 4; kr++) {
            const int k = blockIdx.x * 4 + kr;
            Bp1[((size_t)(k >> 3) * 512 + n) * 8 + (k & 7)] =
                (_Float16)ew1[(size_t)k * 256 + n];
            Bp1[((size_t)(k >> 3) * 512 + 256 + n) * 8 + (k & 7)] =
                (_Float16)ew1[(size_t)(256 + k) * 256 + n];
        }
    }
}

// ---------------- pre (MFMA): [P|Q] = h @ [W_top|W_bot] (+b1 on P) ----------
// 32 nodes/block, 256 threads; P,Q stored f16.
__global__ __launch_bounds__(256) void k_pre(const float* __restrict__ h,
                                             const _Float16* __restrict__ Bp1,
                                             const float* __restrict__ eb1,
                                             _Float16* __restrict__ P,
                                             _Float16* __restrict__ Q) {
    __shared__ f16x8 Ap[32 * 32];   // 16 KB: 32 k-chunks x 32 nodes
    const int tid = threadIdx.x;
    const int l = tid & 63;
    const int w = tid >> 6;
    const int l31 = l & 31;
    const int hh = l >> 5;
    const int n0 = blockIdx.x * 32;

    // stage h (f32 -> f16, A-frag layout)
    {
        const int kb = tid & 31;
        const int eb = tid >> 5;
        #pragma unroll
        for (int i = 0; i < 4; i++) {
            const int e = eb + i * 8;
            const float4 v0 = *(const float4*)(h + (size_t)(n0 + e) * H + kb * 8);
            const float4 v1 = *(const float4*)(h + (size_t)(n0 + e) * H + kb * 8 + 4);
            f16x8 pk;
            pk[0] = (_Float16)v0.x; pk[1] = (_Float16)v0.y;
            pk[2] = (_Float16)v0.z; pk[3] = (_Float16)v0.w;
            pk[4] = (_Float16)v1.x; pk[5] = (_Float16)v1.y;
            pk[6] = (_Float16)v1.z; pk[7] = (_Float16)v1.w;
            Ap[kb * 32 + (e ^ (kb & 7))] = pk;
        }
    }
    __syncthreads();

    const f16x8* Bv = (const f16x8*)Bp1;
    f32x16 acc[4];
    #pragma unroll
    for (int nt = 0; nt < 4; nt++)
        #pragma unroll
        for (int r = 0; r < 16; r++) acc[nt][r] = 0.0f;

    #pragma unroll 4
    for (int kk = 0; kk < 16; kk++) {
        const int kb = kk * 2 + hh;
        const f16x8 a = Ap[kb * 32 + (l31 ^ (kb & 7))];
        #pragma unroll
        for (int nt = 0; nt < 4; nt++) {
            const f16x8 b = Bv[(size_t)kb * 512 + w * 128 + nt * 32 + l31];
            acc[nt] = __builtin_amdgcn_mfma_f32_32x32x16_f16(a, b, acc[nt], 0, 0, 0);
        }
    }

    #pragma unroll
    for (int nt = 0; nt < 4; nt++) {
        const int col = w * 128 + nt * 32 + l31;
        const float bias = (col < 256) ? eb1[col] : 0.0f;
        #pragma unroll
        for (int r = 0; r < 16; r++) {
            const int node = n0 + (r & 3) + 8 * (r >> 2) + 4 * hh;
            const float v = acc[nt][r] + bias;
            if (col < 256) P[(size_t)node * H + col] = (_Float16)v;
            else           Q[(size_t)node * H + col - 256] = (_Float16)v;
        }
    }
}

// ---------------- edge kernel (MFMA, col-sorted edges, f16 P/Q) -------------
__global__ __launch_bounds__(256) void k_edge(
    const float* __restrict__ x, const int* __restrict__ ei,
    const int* __restrict__ perm,
    const _Float16* __restrict__ P, const _Float16* __restrict__ Q,
    const float* __restrict__ ew1,
    const _Float16* __restrict__ Bp2, const float* __restrict__ eb2,
    const _Float16* __restrict__ Bp3, const float* __restrict__ cb1,
    const float* __restrict__ cw2,
    float* __restrict__ msg, float* __restrict__ xout) {
    __shared__ f16x8 Ap[32 * 64];     // 32 KB: m, then m_ij (A-fragment layout)
    __shared__ float sdiff[TE][4];
    __shared__ int srow[TE];
    __shared__ int scol[TE];
    __shared__ float scw[TE];

    const int tid = threadIdx.x;
    const int e0blk = blockIdx.x * TE;
    const int l = tid & 63;
    const int w = tid >> 6;
    const int l31 = l & 31;
    const int hh = l >> 5;
    const int rb = w >> 1;
    const int chb = (w & 1) * 128;

    if (tid < TE) {
        const int e = perm[e0blk + tid];
        const int r = ei[e];
        const int c = ei[NE + e];
        const float dx = x[r * 3 + 0] - x[c * 3 + 0];
        const float dy = x[r * 3 + 1] - x[c * 3 + 1];
        const float dz = x[r * 3 + 2] - x[c * 3 + 2];
        srow[tid] = r; scol[tid] = c;
        sdiff[tid][0] = dx; sdiff[tid][1] = dy; sdiff[tid][2] = dz;
        sdiff[tid][3] = dx * dx + dy * dy + dz * dz;
        scw[tid] = 0.0f;
    }
    __syncthreads();

    // ---- stage m = silu(P[row] + Q[col] + dsq*wd) into Ap (f16, A-layout) ----
    {
        const f16x8* Pv = (const f16x8*)P;
        const f16x8* Qv = (const f16x8*)Q;
        const int kb = tid & 31;
        const int eb = tid >> 5;
        const float4 wd0 = *(const float4*)(ew1 + (size_t)512 * H + kb * 8);
        const float4 wd1 = *(const float4*)(ew1 + (size_t)512 * H + kb * 8 + 4);
        #pragma unroll 2
        for (int i = 0; i < 8; i++) {
            const int e = eb + i * 8;
            const float dsq = sdiff[e][3];
            const f16x8 pr = Pv[(size_t)srow[e] * 32 + kb];
            const f16x8 qr = Qv[(size_t)scol[e] * 32 + kb];
            f16x8 pk;
            pk[0] = (_Float16)silu1((float)pr[0] + (float)qr[0] + dsq * wd0.x);
            pk[1] = (_Float16)silu1((float)pr[1] + (float)qr[1] + dsq * wd0.y);
            pk[2] = (_Float16)silu1((float)pr[2] + (float)qr[2] + dsq * wd0.z);
            pk[3] = (_Float16)silu1((float)pr[3] + (float)qr[3] + dsq * wd0.w);
            pk[4] = (_Float16)silu1((float)pr[4] + (float)qr[4] + dsq * wd1.x);
            pk[5] = (_Float16)silu1((float)pr[5] + (float)qr[5] + dsq * wd1.y);
            pk[6] = (_Float16)silu1((float)pr[6] + (float)qr[6] + dsq * wd1.z);
            pk[7] = (_Float16)silu1((float)pr[7] + (float)qr[7] + dsq * wd1.w);
            Ap[kb * 64 + (e ^ (kb & 7))] = pk;
        }
    }
    __syncthreads();

    const f16x8* Bp2v = (const f16x8*)Bp2;
    const f16x8* Bp3v = (const f16x8*)Bp3;

    // ---- GEMM2: m_ij = silu(m @ e_w2 + e_b2) ----
    f32x16 acc[4];
    #pragma unroll
    for (int nt = 0; nt < 4; nt++)
        #pragma unroll
        for (int r = 0; r < 16; r++) acc[nt][r] = 0.0f;

    #pragma unroll 4
    for (int kk = 0; kk < 16; kk++) {
        const int kb = kk * 2 + hh;
        const f16x8 a = Ap[kb * 64 + ((rb * 32 + l31) ^ (kb & 7))];
        #pragma unroll
        for (int nt = 0; nt < 4; nt++) {
            const f16x8 b = Bp2v[(size_t)kb * 256 + chb + nt * 32 + l31];
            acc[nt] = __builtin_amdgcn_mfma_f32_32x32x16_f16(a, b, acc[nt], 0, 0, 0);
        }
    }

    float mij[4][16];
    #pragma unroll
    for (int nt = 0; nt < 4; nt++) {
        const float bias = eb2[chb + nt * 32 + l31];
        #pragma unroll
        for (int r = 0; r < 16; r++) mij[nt][r] = silu1(acc[nt][r] + bias);
    }

    __syncthreads();   // all waves done reading m from Ap

    // write m_ij into Ap (A-fragment layout) for GEMM3 + segmented reduction
    {
        _Float16* Apf = (_Float16*)Ap;
        #pragma unroll
        for (int nt = 0; nt < 4; nt++) {
            const int c = chb + nt * 32 + l31;
            const int kb2 = c >> 3;
            const int j = c & 7;
            #pragma unroll
            for (int r = 0; r < 16; r++) {
                const int e = rb * 32 + (r & 3) + 8 * (r >> 2) + 4 * hh;
                Apf[(size_t)(kb2 * 64 + (e ^ (kb2 & 7))) * 8 + j] = (_Float16)mij[nt][r];
            }
        }
    }
    __syncthreads();

    // ---- GEMM3: p = m_ij @ c_w1 + c_b1; cw = silu(p) . c_w2 ----
    #pragma unroll
    for (int nt = 0; nt < 4; nt++)
        #pragma unroll
        for (int r = 0; r < 16; r++) acc[nt][r] = 0.0f;

    #pragma unroll 4
    for (int kk = 0; kk < 16; kk++) {
        const int kb = kk * 2 + hh;
        const f16x8 a = Ap[kb * 64 + ((rb * 32 + l31) ^ (kb & 7))];
        #pragma unroll
        for (int nt = 0; nt < 4; nt++) {
            const f16x8 b = Bp3v[(size_t)kb * 256 + chb + nt * 32 + l31];
            acc[nt] = __builtin_amdgcn_mfma_f32_32x32x16_f16(a, b, acc[nt], 0, 0, 0);
        }
    }

    {
        float part[16];
        #pragma unroll
        for (int r = 0; r < 16; r++) part[r] = 0.0f;
        #pragma unroll
        for (int nt = 0; nt < 4; nt++) {
            const int c = chb + nt * 32 + l31;
            const float bias = cb1[c];
            const float cwv = cw2[c];
            #pragma unroll
            for (int r = 0; r < 16; r++)
                part[r] += silu1(acc[nt][r] + bias) * cwv;
        }
        #pragma unroll
        for (int m = 1; m < 32; m <<= 1) {
            #pragma unroll
            for (int r = 0; r < 16; r++) part[r] += __shfl_xor(part[r], m);
        }
        if (l31 == 0) {
            #pragma unroll
            for (int r = 0; r < 16; r++) {
                const int e = rb * 32 + (r & 3) + 8 * (r >> 2) + 4 * hh;
                atomicAdd(&scw[e], part[r]);
            }
        }
    }

    // ---- msg segmented reduction: cols sorted within block ----
    {
        const _Float16* Apf = (const _Float16*)Ap;
        const int kb = tid >> 3;
        const int j = tid & 7;
        float accm = 0.0f;
        #pragma unroll 4
        for (int e = 0; e < TE; e++) {
            accm += (float)Apf[(size_t)(kb * 64 + (e ^ (kb & 7))) * 8 + j];
            const int col = scol[e];
            const int nxt = (e == TE - 1) ? -1 : scol[e + 1];
            if (col != nxt) {
                atomicAdd(msg + (size_t)col * H + tid, accm);
                accm = 0.0f;
            }
        }
    }
    __syncthreads();   // scw complete

    if (tid < 3) {
        const int d = tid;
        float accc = 0.0f;
        for (int e = 0; e < TE; e++) {
            accc += scw[e] * sdiff[e][d];
            const int col = scol[e];
            const int nxt = (e == TE - 1) ? -1 : scol[e + 1];
            if (col != nxt) {
                atomicAdd(xout + (size_t)col * 3 + d, accc);
                accc = 0.0f;
            }
        }
    }
}

// ---------------- node kernel (MFMA): 32 nodes/block, 256 threads -----------
__global__ __launch_bounds__(256) void k_node(
    const float* __restrict__ h, const float* __restrict__ msg,
    const _Float16* __restrict__ BpA, const float* __restrict__ nb1,
    const _Float16* __restrict__ BpB, const float* __restrict__ nb2,
    const float* __restrict__ lng, const float* __restrict__ lnb,
    float* __restrict__ hout) {
    __shared__ f16x8 ApA[64 * 32];  // 32 KB: [h;msg] K=512, A-frag layout
    __shared__ f16x8 Tp[32 * 32];   // 16 KB: t (K=256), A-frag layout
    __shared__ float s1[32];
    __shared__ float s2[32];
    const int tid = threadIdx.x;
    const int l = tid & 63;
    const int w = tid >> 6;
    const int l31 = l & 31;
    const int hh = l >> 5;
    const int n0 = blockIdx.x * 32;

    if (tid < 32) { s1[tid] = 0.0f; s2[tid] = 0.0f; }

    // stage [h ; msg] (f32 -> f16, A-frag layout, kb 0..31 = h, 32..63 = msg)
    {
        const int kb = tid & 31;
        const int eb = tid >> 5;
        #pragma unroll
        for (int i = 0; i < 4; i++) {
            const int e = eb + i * 8;
            #pragma unroll
            for (int half = 0; half < 2; half++) {
                const float* A = half ? msg : h;
                const int kb2 = kb + half * 32;
                const float4 v0 = *(const float4*)(A + (size_t)(n0 + e) * H + kb * 8);
                const float4 v1 = *(const float4*)(A + (size_t)(n0 + e) * H + kb * 8 + 4);
                f16x8 pk;
                pk[0] = (_Float16)v0.x; pk[1] = (_Float16)v0.y;
                pk[2] = (_Float16)v0.z; pk[3] = (_Float16)v0.w;
                pk[4] = (_Float16)v1.x; pk[5] = (_Float16)v1.y;
                pk[6] = (_Float16)v1.z; pk[7] = (_Float16)v1.w;
                ApA[kb2 * 32 + (e ^ (kb2 & 7))] = pk;
            }
        }
    }
    __syncthreads();

    const f16x8* BvA = (const f16x8*)BpA;
    const f16x8* BvB = (const f16x8*)BpB;

    // ---- GEMM A: t = silu([h;msg] @ n_w1 + n_b1), K=512 ----
    f32x16 acc[2];
    #pragma unroll
    for (int nt = 0; nt < 2; nt++)
        #pragma unroll
        for (int r = 0; r < 16; r++) acc[nt][r] = 0.0f;

    #pragma unroll 4
    for (int kk = 0; kk < 32; kk++) {
        const int kb = kk * 2 + hh;
        const f16x8 a = ApA[kb * 32 + (l31 ^ (kb & 7))];
        #pragma unroll
        for (int nt = 0; nt < 2; nt++) {
            const f16x8 b = BvA[(size_t)kb * 256 + w * 64 + nt * 32 + l31];
            acc[nt] = __builtin_amdgcn_mfma_f32_32x32x16_f16(a, b, acc[nt], 0, 0, 0);
        }
    }

    // t -> Tp (A-frag layout for GEMM B)
    {
        _Float16* Tpf = (_Float16*)Tp;
        #pragma unroll
        for (int nt = 0; nt < 2; nt++) {
            const int col = w * 64 + nt * 32 + l31;
            const float bias = nb1[col];
            const int kb2 = col >> 3;
            const int j = col & 7;
            #pragma unroll
            for (int r = 0; r < 16; r++) {
                const int e = (r & 3) + 8 * (r >> 2) + 4 * hh;
                Tpf[(size_t)(kb2 * 32 + (e ^ (kb2 & 7))) * 8 + j] =
                    (_Float16)silu1(acc[nt][r] + bias);
            }
        }
    }
    __syncthreads();

    // ---- GEMM B: h_new = t @ n_w2 + n_b2; y = h + h_new ----
    f32x16 y[2];
    #pragma unroll
    for (int nt = 0; nt < 2; nt++)
        #pragma unroll
        for (int r = 0; r < 16; r++) y[nt][r] = 0.0f;

    #pragma unroll 4
    for (int kk = 0; kk < 16; kk++) {
        const int kb = kk * 2 + hh;
        const f16x8 a = Tp[kb * 32 + (l31 ^ (kb & 7))];
        #pragma unroll
        for (int nt = 0; nt < 2; nt++) {
            const f16x8 b = BvB[(size_t)kb * 256 + w * 64 + nt * 32 + l31];
            y[nt] = __builtin_amdgcn_mfma_f32_32x32x16_f16(a, b, y[nt], 0, 0, 0);
        }
    }

    float t1[16], t2[16];
    #pragma unroll
    for (int r = 0; r < 16; r++) { t1[r] = 0.0f; t2[r] = 0.0f; }
    #pragma unroll
    for (int nt = 0; nt < 2; nt++) {
        const int col = w * 64 + nt * 32 + l31;
        const float bias = nb2[col];
        #pragma unroll
        for (int r = 0; r < 16; r++) {
            const int node = n0 + (r & 3) + 8 * (r >> 2) + 4 * hh;
            const float v = y[nt][r] + bias + h[(size_t)node * H + col];
            y[nt][r] = v;
            t1[r] += v;
            t2[r] += v * v;
        }
    }
    #pragma unroll
    for (int m = 1; m < 32; m <<= 1) {
        #pragma unroll
        for (int r = 0; r < 16; r++) {
            t1[r] += __shfl_xor(t1[r], m);
            t2[r] += __shfl_xor(t2[r], m);
        }
    }
    if (l31 == 0) {
        #pragma unroll
        for (int r = 0; r < 16; r++) {
            const int row = (r & 3) + 8 * (r >> 2) + 4 * hh;
            atomicAdd(&s1[row], t1[r]);
            atomicAdd(&s2[row], t2[r]);
        }
    }
    __syncthreads();

    #pragma unroll
    for (int nt = 0; nt < 2; nt++) {
        const int col = w * 64 + nt * 32 + l31;
        const float g = lng[col];
        const float bb = lnb[col];
        #pragma unroll
        for (int r = 0; r < 16; r++) {
            const int row = (r & 3) + 8 * (r >> 2) + 4 * hh;
            const int node = n0 + row;
            const float mu = s1[row] * (1.0f / H);
            const float var = s2[row] * (1.0f / H) - mu * mu;
            const float rs = rsqrtf(var + LN_EPS);
            hout[(size_t)node * H + col] = (y[nt][r] - mu) * rs * g + bb;
        }
    }
}

extern "C" void kernel_launch(void* const* d_in, const int* in_sizes, int n_in,
                              void* d_out, int out_size, void* d_ws, size_t ws_size,
                              hipStream_t stream) {
    const float* h   = (const float*)d_in[0];
    const float* x   = (const float*)d_in[1];
    const int*   ei  = (const int*)d_in[2];
    const float* ew1 = (const float*)d_in[3];
    const float* eb1 = (const float*)d_in[4];
    const float* ew2 = (const float*)d_in[5];
    const float* eb2 = (const float*)d_in[6];
    const float* cw1 = (const float*)d_in[7];
    const float* cb1 = (const float*)d_in[8];
    const float* cw2 = (const float*)d_in[9];
    const float* nw1 = (const float*)d_in[10];
    const float* nb1 = (const float*)d_in[11];
    const float* nw2 = (const float*)d_in[12];
    const float* nb2 = (const float*)d_in[13];
    const float* lng = (const float*)d_in[14];
    const float* lnb = (const float*)d_in[15];

    float* hout = (float*)d_out;
    float* xout = hout + (size_t)NN * H;

    float* msg = (float*)d_ws;                              // NN*H f32
    _Float16* P   = (_Float16*)(msg + (size_t)NN * H);      // NN*H f16
    _Float16* Qq  = P + (size_t)NN * H;                     // NN*H f16
    _Float16* Bp2 = Qq + (size_t)NN * H;                    // 256*256
    _Float16* Bp3 = Bp2 + 256 * 256;
    _Float16* BpB = Bp3 + 256 * 256;
    _Float16* BpA = BpB + 256 * 256;                        // 512*256
    _Float16* Bp1 = BpA + 512 * 256;                        // 256*512
    int* bins   = (int*)(Bp1 + 256 * 512);
    int* cursor = bins + NN;
    int* perm   = cursor + NN;

    k_init<<<640, 256, 0, stream>>>(x, msg, xout, bins);
    k_hist<<<(NE + 255) / 256, 256, 0, stream>>>(ei, bins);
    k_scan<<<1, 1024, 0, stream>>>(bins, cursor);
    k_scatter<<<(NE + 255) / 256, 256, 0, stream>>>(ei, cursor, perm);
    k_pack<<<dim3(128, 5), 256, 0, stream>>>(ew2, cw1, nw2, nw1, ew1,
                                             Bp2, Bp3, BpB, BpA, Bp1);
    k_pre<<<NN / 32, 256, 0, stream>>>(h, Bp1, eb1, P, Qq);
    k_edge<<<NE / TE, 256, 0, stream>>>(x, ei, perm, P, Qq, ew1, Bp2, eb2,
                                        Bp3, cb1, cw2, msg, xout);
    k_node<<<NN / 32, 256, 0, stream>>>(h, msg, BpA, nb1, BpB, nb2,
                                        lng, lnb, hout);
}

// Round 5
// 475.764 us; speedup vs baseline: 3.5393x; 1.1097x over previous
//
#include <hip/hip_runtime.h>
#include <hip/hip_fp16.h>
#include <math.h>

#define NN 20000
#define NE 320000
#define H 256
#define LN_EPS 1e-5f
#define TE 64   // edges per block (edge kernel)

typedef _Float16 f16x8 __attribute__((ext_vector_type(8)));
typedef float f32x16 __attribute__((ext_vector_type(16)));

__device__ __forceinline__ float silu1(float v) {
    return __fdividef(v, 1.0f + __expf(-v));
}

// ---------------- counting sort by col ----------------
// misc zones: [0,1250) hist, [1250,1485) xcopy, [1485,2125) pack, 2125 wdist
__global__ void k_misc(const int* __restrict__ ei, int* __restrict__ bins,
                       const float* __restrict__ x, float* __restrict__ xout,
                       const float* __restrict__ ew2, const float* __restrict__ cw1,
                       const float* __restrict__ nw2, const float* __restrict__ nw1,
                       const float* __restrict__ ew1,
                       _Float16* __restrict__ Bp2, _Float16* __restrict__ Bp3,
                       _Float16* __restrict__ BpB, _Float16* __restrict__ BpA,
                       _Float16* __restrict__ Bp1, _Float16* __restrict__ wdh) {
    const int b = blockIdx.x;
    const int tid = threadIdx.x;
    if (b < 1250) {                           // hist
        atomicAdd(&bins[ei[NE + b * 256 + tid]], 1);
    } else if (b < 1485) {                    // xcopy
        const int i = (b - 1250) * 256 + tid;
        if (i < NN * 3) xout[i] = x[i];
    } else if (b < 2125) {                    // weight pack
        const int pb = b - 1485;
        const int which = pb >> 7;
        const int bx = pb & 127;
        const int n = tid;
        if (which < 3) {                      // K=256, N=256
            if (bx >= 64) return;
            const float* W = (which == 0) ? ew2 : (which == 1) ? cw1 : nw2;
            _Float16* Bp = (which == 0) ? Bp2 : (which == 1) ? Bp3 : BpB;
            #pragma unroll
            for (int kr = 0; kr < 4; kr++) {
                const int k = bx * 4 + kr;
                Bp[((size_t)(k >> 3) * 256 + n) * 8 + (k & 7)] =
                    (_Float16)W[(size_t)k * 256 + n];
            }
        } else if (which == 3) {              // nw1: K=512, N=256
            #pragma unroll
            for (int kr = 0; kr < 4; kr++) {
                const int k = bx * 4 + kr;
                BpA[((size_t)(k >> 3) * 256 + n) * 8 + (k & 7)] =
                    (_Float16)nw1[(size_t)k * 256 + n];
            }
        } else {                              // ew1 combined: K=256, N=512
            if (bx >= 64) return;
            #pragma unroll
            for (int kr = 0; kr < 4; kr++) {
                const int k = bx * 4 + kr;
                Bp1[((size_t)(k >> 3) * 512 + n) * 8 + (k & 7)] =
                    (_Float16)ew1[(size_t)k * 256 + n];
                Bp1[((size_t)(k >> 3) * 512 + 256 + n) * 8 + (k & 7)] =
                    (_Float16)ew1[(size_t)(256 + k) * 256 + n];
            }
        }
    } else {                                  // wdist row of ew1 -> f16
        wdh[tid] = (_Float16)ew1[(size_t)512 * H + tid];
    }
}

// shuffle-based exclusive scan of 20000 bins, one block of 1024 threads
__global__ __launch_bounds__(1024) void k_scan(const int* __restrict__ bins,
                                               int* __restrict__ cursor) {
    __shared__ int wsum[16];
    __shared__ int wbase[16];
    const int tid = threadIdx.x;
    const int lane = tid & 63;
    const int wid = tid >> 6;
    const int base = tid * 20;
    int loc[20];
    int sum = 0;
    #pragma unroll
    for (int j = 0; j < 20; j++) {
        const int idx = base + j;
        const int v = (idx < NN) ? bins[idx] : 0;
        loc[j] = sum;
        sum += v;
    }
    int inc = sum;
    #pragma unroll
    for (int off = 1; off < 64; off <<= 1) {
        const int t = __shfl_up(inc, off);
        if (lane >= off) inc += t;
    }
    if (lane == 63) wsum[wid] = inc;
    __syncthreads();
    if (tid < 64) {
        int v = (tid < 16) ? wsum[tid] : 0;
        int inc2 = v;
        #pragma unroll
        for (int off = 1; off < 16; off <<= 1) {
            const int t = __shfl_up(inc2, off);
            if (lane >= off) inc2 += t;
        }
        if (tid < 16) wbase[tid] = inc2 - v;
    }
    __syncthreads();
    const int excl = wbase[wid] + inc - sum;
    #pragma unroll
    for (int j = 0; j < 20; j++) {
        const int idx = base + j;
        if (idx < NN) cursor[idx] = excl + loc[j];
    }
}

__global__ void k_scatter(const int* __restrict__ ei, int* __restrict__ cursor,
                          int* __restrict__ perm) {
    const int e = blockIdx.x * blockDim.x + threadIdx.x;
    if (e < NE) {
        const int c = ei[NE + e];
        const int pos = atomicAdd(&cursor[c], 1);
        perm[pos] = e;
    }
}

// ---------------- pre (MFMA): [P|Q] = h @ [W_top|W_bot] (+b1 on P) ----------
__global__ __launch_bounds__(256) void k_pre(const float* __restrict__ h,
                                             const _Float16* __restrict__ Bp1,
                                             const float* __restrict__ eb1,
                                             _Float16* __restrict__ P,
                                             _Float16* __restrict__ Q) {
    __shared__ f16x8 Ap[32 * 32];
    const int tid = threadIdx.x;
    const int l = tid & 63;
    const int w = tid >> 6;
    const int l31 = l & 31;
    const int hh = l >> 5;
    const int n0 = blockIdx.x * 32;

    {
        const int kb = tid & 31;
        const int eb = tid >> 5;
        #pragma unroll
        for (int i = 0; i < 4; i++) {
            const int e = eb + i * 8;
            const float4 v0 = *(const float4*)(h + (size_t)(n0 + e) * H + kb * 8);
            const float4 v1 = *(const float4*)(h + (size_t)(n0 + e) * H + kb * 8 + 4);
            f16x8 pk;
            pk[0] = (_Float16)v0.x; pk[1] = (_Float16)v0.y;
            pk[2] = (_Float16)v0.z; pk[3] = (_Float16)v0.w;
            pk[4] = (_Float16)v1.x; pk[5] = (_Float16)v1.y;
            pk[6] = (_Float16)v1.z; pk[7] = (_Float16)v1.w;
            Ap[kb * 32 + (e ^ (kb & 7))] = pk;
        }
    }
    __syncthreads();

    const f16x8* Bv = (const f16x8*)Bp1;
    f32x16 acc[4];
    #pragma unroll
    for (int nt = 0; nt < 4; nt++)
        #pragma unroll
        for (int r = 0; r < 16; r++) acc[nt][r] = 0.0f;

    #pragma unroll 4
    for (int kk = 0; kk < 16; kk++) {
        const int kb = kk * 2 + hh;
        const f16x8 a = Ap[kb * 32 + (l31 ^ (kb & 7))];
        #pragma unroll
        for (int nt = 0; nt < 4; nt++) {
            const f16x8 b = Bv[(size_t)kb * 512 + w * 128 + nt * 32 + l31];
            acc[nt] = __builtin_amdgcn_mfma_f32_32x32x16_f16(a, b, acc[nt], 0, 0, 0);
        }
    }

    #pragma unroll
    for (int nt = 0; nt < 4; nt++) {
        const int col = w * 128 + nt * 32 + l31;
        const float bias = (col < 256) ? eb1[col] : 0.0f;
        #pragma unroll
        for (int r = 0; r < 16; r++) {
            const int node = n0 + (r & 3) + 8 * (r >> 2) + 4 * hh;
            const float v = acc[nt][r] + bias;
            if (col < 256) P[(size_t)node * H + col] = (_Float16)v;
            else           Q[(size_t)node * H + col - 256] = (_Float16)v;
        }
    }
}

// ---------------- edge kernel: 64 edges/block, 128 threads, M=64/wave -------
// Each wave: all 64 edges (two 32-row MFMA tiles) x 128 channels (w*128).
__global__ __launch_bounds__(128, 2) void k_edge(
    const float* __restrict__ x, const int* __restrict__ ei,
    const int* __restrict__ perm,
    const _Float16* __restrict__ P, const _Float16* __restrict__ Q,
    const _Float16* __restrict__ wdh,
    const _Float16* __restrict__ Bp2, const float* __restrict__ eb2,
    const _Float16* __restrict__ Bp3, const float* __restrict__ cb1,
    const float* __restrict__ cw2,
    float* __restrict__ msg, float* __restrict__ xout) {
    __shared__ f16x8 Ap[32 * 64];     // 32 KB: m, then m_ij (A-frag layout)
    __shared__ float sdiff[TE][4];
    __shared__ int srow[TE];
    __shared__ int scol[TE];
    __shared__ float scw[TE];

    const int tid = threadIdx.x;      // 0..127
    const int e0blk = blockIdx.x * TE;
    const int l = tid & 63;
    const int w = tid >> 6;           // channel half: w*128
    const int l31 = l & 31;
    const int hh = l >> 5;

    if (tid < TE) {
        const int e = perm[e0blk + tid];
        const int r = ei[e];
        const int c = ei[NE + e];
        const float dx = x[r * 3 + 0] - x[c * 3 + 0];
        const float dy = x[r * 3 + 1] - x[c * 3 + 1];
        const float dz = x[r * 3 + 2] - x[c * 3 + 2];
        srow[tid] = r; scol[tid] = c;
        sdiff[tid][0] = dx; sdiff[tid][1] = dy; sdiff[tid][2] = dz;
        sdiff[tid][3] = dx * dx + dy * dy + dz * dz;
        scw[tid] = 0.0f;
    }
    __syncthreads();

    // ---- stage m = silu(P[row]+Q[col]+dsq*wd), packed f16 math ----
    {
        const f16x8* Pv = (const f16x8*)P;
        const f16x8* Qv = (const f16x8*)Q;
        const int kb = tid & 31;
        const int eb = tid >> 5;      // 0..3
        union { f16x8 v; __half2 h[4]; } wdu;
        wdu.v = ((const f16x8*)wdh)[kb];
        const __half2 one2 = __float2half2_rn(1.0f);
        #pragma unroll 4
        for (int i = 0; i < 16; i++) {
            const int e = eb + i * 4;
            const __half2 d2 = __float2half2_rn(sdiff[e][3]);
            union { f16x8 v; __half2 h[4]; } pu, qu, su;
            pu.v = Pv[(size_t)srow[e] * 32 + kb];
            qu.v = Qv[(size_t)scol[e] * 32 + kb];
            #pragma unroll
            for (int j = 0; j < 4; j++) {
                const __half2 s = __hfma2(wdu.h[j], d2, __hadd2(pu.h[j], qu.h[j]));
                const __half2 ex = h2exp(__hneg2(s));
                const __half2 dn = __hadd2(one2, ex);
                su.h[j] = __hmul2(s, h2rcp(dn));
            }
            Ap[kb * 64 + (e ^ (kb & 7))] = su.v;
        }
    }
    __syncthreads();

    const f16x8* Bp2v = (const f16x8*)Bp2;
    const f16x8* Bp3v = (const f16x8*)Bp3;

    // ---- GEMM2: m_ij = silu(m @ e_w2 + e_b2), M=64 per wave ----
    f32x16 acc0[4], acc1[4];
    #pragma unroll
    for (int nt = 0; nt < 4; nt++)
        #pragma unroll
        for (int r = 0; r < 16; r++) { acc0[nt][r] = 0.0f; acc1[nt][r] = 0.0f; }

    #pragma unroll 2
    for (int kk = 0; kk < 16; kk++) {
        const int kb = kk * 2 + hh;
        const f16x8 a0 = Ap[kb * 64 + (l31 ^ (kb & 7))];
        const f16x8 a1 = Ap[kb * 64 + ((32 + l31) ^ (kb & 7))];
        #pragma unroll
        for (int nt = 0; nt < 4; nt++) {
            const f16x8 b = Bp2v[(size_t)kb * 256 + w * 128 + nt * 32 + l31];
            acc0[nt] = __builtin_amdgcn_mfma_f32_32x32x16_f16(a0, b, acc0[nt], 0, 0, 0);
            acc1[nt] = __builtin_amdgcn_mfma_f32_32x32x16_f16(a1, b, acc1[nt], 0, 0, 0);
        }
    }

    __syncthreads();   // all waves done reading m from Ap

    // silu + bias, write m_ij into Ap (A-frag layout)
    {
        _Float16* Apf = (_Float16*)Ap;
        #pragma unroll
        for (int nt = 0; nt < 4; nt++) {
            const int c = w * 128 + nt * 32 + l31;
            const float bias = eb2[c];
            const int kb2 = c >> 3;
            const int j = c & 7;
            #pragma unroll
            for (int r = 0; r < 16; r++) {
                const int e0 = (r & 3) + 8 * (r >> 2) + 4 * hh;
                Apf[(size_t)(kb2 * 64 + (e0 ^ (kb2 & 7))) * 8 + j] =
                    (_Float16)silu1(acc0[nt][r] + bias);
                Apf[(size_t)(kb2 * 64 + ((e0 + 32) ^ (kb2 & 7))) * 8 + j] =
                    (_Float16)silu1(acc1[nt][r] + bias);
            }
        }
    }
    __syncthreads();

    // ---- GEMM3: p = m_ij @ c_w1 + c_b1; cw = silu(p) . c_w2 ----
    #pragma unroll
    for (int nt = 0; nt < 4; nt++)
        #pragma unroll
        for (int r = 0; r < 16; r++) { acc0[nt][r] = 0.0f; acc1[nt][r] = 0.0f; }

    #pragma unroll 2
    for (int kk = 0; kk < 16; kk++) {
        const int kb = kk * 2 + hh;
        const f16x8 a0 = Ap[kb * 64 + (l31 ^ (kb & 7))];
        const f16x8 a1 = Ap[kb * 64 + ((32 + l31) ^ (kb & 7))];
        #pragma unroll
        for (int nt = 0; nt < 4; nt++) {
            const f16x8 b = Bp3v[(size_t)kb * 256 + w * 128 + nt * 32 + l31];
            acc0[nt] = __builtin_amdgcn_mfma_f32_32x32x16_f16(a0, b, acc0[nt], 0, 0, 0);
            acc1[nt] = __builtin_amdgcn_mfma_f32_32x32x16_f16(a1, b, acc1[nt], 0, 0, 0);
        }
    }

    {
        float p0[16], p1[16];
        #pragma unroll
        for (int r = 0; r < 16; r++) { p0[r] = 0.0f; p1[r] = 0.0f; }
        #pragma unroll
        for (int nt = 0; nt < 4; nt++) {
            const int c = w * 128 + nt * 32 + l31;
            const float bias = cb1[c];
            const float cwv = cw2[c];
            #pragma unroll
            for (int r = 0; r < 16; r++) {
                p0[r] += silu1(acc0[nt][r] + bias) * cwv;
                p1[r] += silu1(acc1[nt][r] + bias) * cwv;
            }
        }
        #pragma unroll
        for (int m = 1; m < 32; m <<= 1) {
            #pragma unroll
            for (int r = 0; r < 16; r++) {
                p0[r] += __shfl_xor(p0[r], m);
                p1[r] += __shfl_xor(p1[r], m);
            }
        }
        if (l31 == 0) {
            #pragma unroll
            for (int r = 0; r < 16; r++) {
                const int e0 = (r & 3) + 8 * (r >> 2) + 4 * hh;
                atomicAdd(&scw[e0], p0[r]);
                atomicAdd(&scw[e0 + 32], p1[r]);
            }
        }
    }
    __syncthreads();   // scw + m_ij complete

    // ---- msg segmented reduction: each thread owns channels tid, tid+128 ----
    {
        const _Float16* Apf = (const _Float16*)Ap;
        #pragma unroll
        for (int cc = 0; cc < 2; cc++) {
            const int c = tid + cc * 128;
            const int kb = c >> 3;
            const int j = c & 7;
            float accm = 0.0f;
            #pragma unroll 4
            for (int e = 0; e < TE; e++) {
                accm += (float)Apf[(size_t)(kb * 64 + (e ^ (kb & 7))) * 8 + j];
                const int col = scol[e];
                const int nxt = (e == TE - 1) ? -1 : scol[e + 1];
                if (col != nxt) {
                    atomicAdd(msg + (size_t)col * H + c, accm);
                    accm = 0.0f;
                }
            }
        }
    }

    // ---- coord segmented reduction ----
    if (tid < 3) {
        const int d = tid;
        float accc = 0.0f;
        for (int e = 0; e < TE; e++) {
            accc += scw[e] * sdiff[e][d];
            const int col = scol[e];
            const int nxt = (e == TE - 1) ? -1 : scol[e + 1];
            if (col != nxt) {
                atomicAdd(xout + (size_t)col * 3 + d, accc);
                accc = 0.0f;
            }
        }
    }
}

// ---------------- node kernel (MFMA): 32 nodes/block, 256 threads -----------
__global__ __launch_bounds__(256) void k_node(
    const float* __restrict__ h, const float* __restrict__ msg,
    const _Float16* __restrict__ BpA, const float* __restrict__ nb1,
    const _Float16* __restrict__ BpB, const float* __restrict__ nb2,
    const float* __restrict__ lng, const float* __restrict__ lnb,
    float* __restrict__ hout) {
    __shared__ f16x8 ApA[64 * 32];
    __shared__ f16x8 Tp[32 * 32];
    __shared__ float s1[32];
    __shared__ float s2[32];
    const int tid = threadIdx.x;
    const int l = tid & 63;
    const int w = tid >> 6;
    const int l31 = l & 31;
    const int hh = l >> 5;
    const int n0 = blockIdx.x * 32;

    if (tid < 32) { s1[tid] = 0.0f; s2[tid] = 0.0f; }

    {
        const int kb = tid & 31;
        const int eb = tid >> 5;
        #pragma unroll
        for (int i = 0; i < 4; i++) {
            const int e = eb + i * 8;
            #pragma unroll
            for (int half = 0; half < 2; half++) {
                const float* A = half ? msg : h;
                const int kb2 = kb + half * 32;
                const float4 v0 = *(const float4*)(A + (size_t)(n0 + e) * H + kb * 8);
                const float4 v1 = *(const float4*)(A + (size_t)(n0 + e) * H + kb * 8 + 4);
                f16x8 pk;
                pk[0] = (_Float16)v0.x; pk[1] = (_Float16)v0.y;
                pk[2] = (_Float16)v0.z; pk[3] = (_Float16)v0.w;
                pk[4] = (_Float16)v1.x; pk[5] = (_Float16)v1.y;
                pk[6] = (_Float16)v1.z; pk[7] = (_Float16)v1.w;
                ApA[kb2 * 32 + (e ^ (kb2 & 7))] = pk;
            }
        }
    }
    __syncthreads();

    const f16x8* BvA = (const f16x8*)BpA;
    const f16x8* BvB = (const f16x8*)BpB;

    f32x16 acc[2];
    #pragma unroll
    for (int nt = 0; nt < 2; nt++)
        #pragma unroll
        for (int r = 0; r < 16; r++) acc[nt][r] = 0.0f;

    #pragma unroll 4
    for (int kk = 0; kk < 32; kk++) {
        const int kb = kk * 2 + hh;
        const f16x8 a = ApA[kb * 32 + (l31 ^ (kb & 7))];
        #pragma unroll
        for (int nt = 0; nt < 2; nt++) {
            const f16x8 b = BvA[(size_t)kb * 256 + w * 64 + nt * 32 + l31];
            acc[nt] = __builtin_amdgcn_mfma_f32_32x32x16_f16(a, b, acc[nt], 0, 0, 0);
        }
    }

    {
        _Float16* Tpf = (_Float16*)Tp;
        #pragma unroll
        for (int nt = 0; nt < 2; nt++) {
            const int col = w * 64 + nt * 32 + l31;
            const float bias = nb1[col];
            const int kb2 = col >> 3;
            const int j = col & 7;
            #pragma unroll
            for (int r = 0; r < 16; r++) {
                const int e = (r & 3) + 8 * (r >> 2) + 4 * hh;
                Tpf[(size_t)(kb2 * 32 + (e ^ (kb2 & 7))) * 8 + j] =
                    (_Float16)silu1(acc[nt][r] + bias);
            }
        }
    }
    __syncthreads();

    f32x16 y[2];
    #pragma unroll
    for (int nt = 0; nt < 2; nt++)
        #pragma unroll
        for (int r = 0; r < 16; r++) y[nt][r] = 0.0f;

    #pragma unroll 4
    for (int kk = 0; kk < 16; kk++) {
        const int kb = kk * 2 + hh;
        const f16x8 a = Tp[kb * 32 + (l31 ^ (kb & 7))];
        #pragma unroll
        for (int nt = 0; nt < 2; nt++) {
            const f16x8 b = BvB[(size_t)kb * 256 + w * 64 + nt * 32 + l31];
            y[nt] = __builtin_amdgcn_mfma_f32_32x32x16_f16(a, b, y[nt], 0, 0, 0);
        }
    }

    float t1[16], t2[16];
    #pragma unroll
    for (int r = 0; r < 16; r++) { t1[r] = 0.0f; t2[r] = 0.0f; }
    #pragma unroll
    for (int nt = 0; nt < 2; nt++) {
        const int col = w * 64 + nt * 32 + l31;
        const float bias = nb2[col];
        #pragma unroll
        for (int r = 0; r < 16; r++) {
            const int node = n0 + (r & 3) + 8 * (r >> 2) + 4 * hh;
            const float v = y[nt][r] + bias + h[(size_t)node * H + col];
            y[nt][r] = v;
            t1[r] += v;
            t2[r] += v * v;
        }
    }
    #pragma unroll
    for (int m = 1; m < 32; m <<= 1) {
        #pragma unroll
        for (int r = 0; r < 16; r++) {
            t1[r] += __shfl_xor(t1[r], m);
            t2[r] += __shfl_xor(t2[r], m);
        }
    }
    if (l31 == 0) {
        #pragma unroll
        for (int r = 0; r < 16; r++) {
            const int row = (r & 3) + 8 * (r >> 2) + 4 * hh;
            atomicAdd(&s1[row], t1[r]);
            atomicAdd(&s2[row], t2[r]);
        }
    }
    __syncthreads();

    #pragma unroll
    for (int nt = 0; nt < 2; nt++) {
        const int col = w * 64 + nt * 32 + l31;
        const float g = lng[col];
        const float bb = lnb[col];
        #pragma unroll
        for (int r = 0; r < 16; r++) {
            const int row = (r & 3) + 8 * (r >> 2) + 4 * hh;
            const int node = n0 + row;
            const float mu = s1[row] * (1.0f / H);
            const float var = s2[row] * (1.0f / H) - mu * mu;
            const float rs = rsqrtf(var + LN_EPS);
            hout[(size_t)node * H + col] = (y[nt][r] - mu) * rs * g + bb;
        }
    }
}

extern "C" void kernel_launch(void* const* d_in, const int* in_sizes, int n_in,
                              void* d_out, int out_size, void* d_ws, size_t ws_size,
                              hipStream_t stream) {
    const float* h   = (const float*)d_in[0];
    const float* x   = (const float*)d_in[1];
    const int*   ei  = (const int*)d_in[2];
    const float* ew1 = (const float*)d_in[3];
    const float* eb1 = (const float*)d_in[4];
    const float* ew2 = (const float*)d_in[5];
    const float* eb2 = (const float*)d_in[6];
    const float* cw1 = (const float*)d_in[7];
    const float* cb1 = (const float*)d_in[8];
    const float* cw2 = (const float*)d_in[9];
    const float* nw1 = (const float*)d_in[10];
    const float* nb1 = (const float*)d_in[11];
    const float* nw2 = (const float*)d_in[12];
    const float* nb2 = (const float*)d_in[13];
    const float* lng = (const float*)d_in[14];
    const float* lnb = (const float*)d_in[15];

    float* hout = (float*)d_out;
    float* xout = hout + (size_t)NN * H;

    float* msg = (float*)d_ws;                              // NN*H f32
    int* bins = (int*)(msg + (size_t)NN * H);               // NN (memset w/ msg)
    _Float16* P   = (_Float16*)(bins + NN);                 // NN*H f16
    _Float16* Qq  = P + (size_t)NN * H;                     // NN*H f16
    _Float16* Bp2 = Qq + (size_t)NN * H;                    // 256*256
    _Float16* Bp3 = Bp2 + 256 * 256;
    _Float16* BpB = Bp3 + 256 * 256;
    _Float16* BpA = BpB + 256 * 256;                        // 512*256
    _Float16* Bp1 = BpA + 512 * 256;                        // 256*512
    _Float16* wdh = Bp1 + 256 * 512;                        // 256
    int* cursor = (int*)(wdh + 256);
    int* perm   = cursor + NN;

    hipMemsetAsync(d_ws, 0, (size_t)NN * H * 4 + NN * 4, stream);
    k_misc<<<2126, 256, 0, stream>>>(ei, bins, x, xout, ew2, cw1, nw2, nw1, ew1,
                                     Bp2, Bp3, BpB, BpA, Bp1, wdh);
    k_scan<<<1, 1024, 0, stream>>>(bins, cursor);
    k_scatter<<<(NE + 255) / 256, 256, 0, stream>>>(ei, cursor, perm);
    k_pre<<<NN / 32, 256, 0, stream>>>(h, Bp1, eb1, P, Qq);
    k_edge<<<NE / TE, 128, 0, stream>>>(x, ei, perm, P, Qq, wdh, Bp2, eb2,
                                        Bp3, cb1, cw2, msg, xout);
    k_node<<<NN / 32, 256, 0, stream>>>(h, msg, BpA, nb1, BpB, nb2,
                                        lng, lnb, hout);
}

// Round 6
// 394.495 us; speedup vs baseline: 4.2684x; 1.2060x over previous
//
#include <hip/hip_runtime.h>
#include <hip/hip_fp16.h>
#include <math.h>

#define NN 20000
#define NE 320000
#define H 256
#define LN_EPS 1e-5f
#define TE 64   // edges per block (edge kernel)

typedef _Float16 f16x8 __attribute__((ext_vector_type(8)));
typedef float f32x16 __attribute__((ext_vector_type(16)));

__device__ __forceinline__ float silu1(float v) {
    return __fdividef(v, 1.0f + __expf(-v));
}

// ---------------- counting sort by col ----------------
// misc zones: [0,1250) hist, [1250,1485) xcopy, [1485,2125) pack, 2125 wdist
__global__ void k_misc(const int* __restrict__ ei, int* __restrict__ bins,
                       const float* __restrict__ x, float* __restrict__ xout,
                       const float* __restrict__ ew2, const float* __restrict__ cw1,
                       const float* __restrict__ nw2, const float* __restrict__ nw1,
                       const float* __restrict__ ew1,
                       _Float16* __restrict__ Bp2, _Float16* __restrict__ Bp3,
                       _Float16* __restrict__ BpB, _Float16* __restrict__ BpA,
                       _Float16* __restrict__ Bp1, _Float16* __restrict__ wdh) {
    const int b = blockIdx.x;
    const int tid = threadIdx.x;
    if (b < 1250) {                           // hist
        atomicAdd(&bins[ei[NE + b * 256 + tid]], 1);
    } else if (b < 1485) {                    // xcopy
        const int i = (b - 1250) * 256 + tid;
        if (i < NN * 3) xout[i] = x[i];
    } else if (b < 2125) {                    // weight pack
        const int pb = b - 1485;
        const int which = pb >> 7;
        const int bx = pb & 127;
        const int n = tid;
        if (which < 3) {                      // K=256, N=256
            if (bx >= 64) return;
            const float* W = (which == 0) ? ew2 : (which == 1) ? cw1 : nw2;
            _Float16* Bp = (which == 0) ? Bp2 : (which == 1) ? Bp3 : BpB;
            #pragma unroll
            for (int kr = 0; kr < 4; kr++) {
                const int k = bx * 4 + kr;
                Bp[((size_t)(k >> 3) * 256 + n) * 8 + (k & 7)] =
                    (_Float16)W[(size_t)k * 256 + n];
            }
        } else if (which == 3) {              // nw1: K=512, N=256
            #pragma unroll
            for (int kr = 0; kr < 4; kr++) {
                const int k = bx * 4 + kr;
                BpA[((size_t)(k >> 3) * 256 + n) * 8 + (k & 7)] =
                    (_Float16)nw1[(size_t)k * 256 + n];
            }
        } else {                              // ew1 combined: K=256, N=512
            if (bx >= 64) return;
            #pragma unroll
            for (int kr = 0; kr < 4; kr++) {
                const int k = bx * 4 + kr;
                Bp1[((size_t)(k >> 3) * 512 + n) * 8 + (k & 7)] =
                    (_Float16)ew1[(size_t)k * 256 + n];
                Bp1[((size_t)(k >> 3) * 512 + 256 + n) * 8 + (k & 7)] =
                    (_Float16)ew1[(size_t)(256 + k) * 256 + n];
            }
        }
    } else {                                  // wdist row of ew1 -> f16
        wdh[tid] = (_Float16)ew1[(size_t)512 * H + tid];
    }
}

// shuffle-based exclusive scan of 20000 bins, one block of 1024 threads
__global__ __launch_bounds__(1024) void k_scan(const int* __restrict__ bins,
                                               int* __restrict__ cursor) {
    __shared__ int wsum[16];
    __shared__ int wbase[16];
    const int tid = threadIdx.x;
    const int lane = tid & 63;
    const int wid = tid >> 6;
    const int base = tid * 20;
    int loc[20];
    int sum = 0;
    #pragma unroll
    for (int j = 0; j < 20; j++) {
        const int idx = base + j;
        const int v = (idx < NN) ? bins[idx] : 0;
        loc[j] = sum;
        sum += v;
    }
    int inc = sum;
    #pragma unroll
    for (int off = 1; off < 64; off <<= 1) {
        const int t = __shfl_up(inc, off);
        if (lane >= off) inc += t;
    }
    if (lane == 63) wsum[wid] = inc;
    __syncthreads();
    if (tid < 64) {
        int v = (tid < 16) ? wsum[tid] : 0;
        int inc2 = v;
        #pragma unroll
        for (int off = 1; off < 16; off <<= 1) {
            const int t = __shfl_up(inc2, off);
            if (lane >= off) inc2 += t;
        }
        if (tid < 16) wbase[tid] = inc2 - v;
    }
    __syncthreads();
    const int excl = wbase[wid] + inc - sum;
    #pragma unroll
    for (int j = 0; j < 20; j++) {
        const int idx = base + j;
        if (idx < NN) cursor[idx] = excl + loc[j];
    }
}

__global__ void k_scatter(const int* __restrict__ ei, int* __restrict__ cursor,
                          int* __restrict__ perm) {
    const int e = blockIdx.x * blockDim.x + threadIdx.x;
    if (e < NE) {
        const int c = ei[NE + e];
        const int pos = atomicAdd(&cursor[c], 1);
        perm[pos] = e;
    }
}

// ---------------- pre (MFMA): [P|Q] = h @ [W_top|W_bot] (+b1 on P) ----------
__global__ __launch_bounds__(256) void k_pre(const float* __restrict__ h,
                                             const _Float16* __restrict__ Bp1,
                                             const float* __restrict__ eb1,
                                             _Float16* __restrict__ P,
                                             _Float16* __restrict__ Q) {
    __shared__ f16x8 Ap[32 * 32];
    const int tid = threadIdx.x;
    const int l = tid & 63;
    const int w = tid >> 6;
    const int l31 = l & 31;
    const int hh = l >> 5;
    const int n0 = blockIdx.x * 32;

    {
        const int kb = tid & 31;
        const int eb = tid >> 5;
        #pragma unroll
        for (int i = 0; i < 4; i++) {
            const int e = eb + i * 8;
            const float4 v0 = *(const float4*)(h + (size_t)(n0 + e) * H + kb * 8);
            const float4 v1 = *(const float4*)(h + (size_t)(n0 + e) * H + kb * 8 + 4);
            f16x8 pk;
            pk[0] = (_Float16)v0.x; pk[1] = (_Float16)v0.y;
            pk[2] = (_Float16)v0.z; pk[3] = (_Float16)v0.w;
            pk[4] = (_Float16)v1.x; pk[5] = (_Float16)v1.y;
            pk[6] = (_Float16)v1.z; pk[7] = (_Float16)v1.w;
            Ap[kb * 32 + (e ^ (kb & 7))] = pk;
        }
    }
    __syncthreads();

    const f16x8* Bv = (const f16x8*)Bp1;
    f32x16 acc[4];
    #pragma unroll
    for (int nt = 0; nt < 4; nt++)
        #pragma unroll
        for (int r = 0; r < 16; r++) acc[nt][r] = 0.0f;

    #pragma unroll 4
    for (int kk = 0; kk < 16; kk++) {
        const int kb = kk * 2 + hh;
        const f16x8 a = Ap[kb * 32 + (l31 ^ (kb & 7))];
        #pragma unroll
        for (int nt = 0; nt < 4; nt++) {
            const f16x8 b = Bv[(size_t)kb * 512 + w * 128 + nt * 32 + l31];
            acc[nt] = __builtin_amdgcn_mfma_f32_32x32x16_f16(a, b, acc[nt], 0, 0, 0);
        }
    }

    #pragma unroll
    for (int nt = 0; nt < 4; nt++) {
        const int col = w * 128 + nt * 32 + l31;
        const float bias = (col < 256) ? eb1[col] : 0.0f;
        #pragma unroll
        for (int r = 0; r < 16; r++) {
            const int node = n0 + (r & 3) + 8 * (r >> 2) + 4 * hh;
            const float v = acc[nt][r] + bias;
            if (col < 256) P[(size_t)node * H + col] = (_Float16)v;
            else           Q[(size_t)node * H + col - 256] = (_Float16)v;
        }
    }
}

// ---------------- edge kernel: 64 edges/block, 256 threads, 4 waves ---------
// Wave w: M=64 (edges, two 32-row tiles a0/a1) x N=64 (channels w*64..+63).
__global__ __launch_bounds__(256, 3) void k_edge(
    const float* __restrict__ x, const int* __restrict__ ei,
    const int* __restrict__ perm,
    const _Float16* __restrict__ P, const _Float16* __restrict__ Q,
    const _Float16* __restrict__ wdh,
    const _Float16* __restrict__ Bp2, const float* __restrict__ eb2,
    const _Float16* __restrict__ Bp3, const float* __restrict__ cb1,
    const float* __restrict__ cw2,
    float* __restrict__ msg, float* __restrict__ xout) {
    __shared__ f16x8 Ap[32 * 64];     // 32 KB: m, then m_ij (A-frag layout)
    __shared__ float sdiff[TE][4];
    __shared__ int srow[TE];
    __shared__ int scol[TE];
    __shared__ float scw[TE];

    const int tid = threadIdx.x;      // 0..255
    const int e0blk = blockIdx.x * TE;
    const int l = tid & 63;
    const int w = tid >> 6;           // channel quarter: w*64
    const int l31 = l & 31;
    const int hh = l >> 5;

    if (tid < TE) {
        const int e = perm[e0blk + tid];
        const int r = ei[e];
        const int c = ei[NE + e];
        const float dx = x[r * 3 + 0] - x[c * 3 + 0];
        const float dy = x[r * 3 + 1] - x[c * 3 + 1];
        const float dz = x[r * 3 + 2] - x[c * 3 + 2];
        srow[tid] = r; scol[tid] = c;
        sdiff[tid][0] = dx; sdiff[tid][1] = dy; sdiff[tid][2] = dz;
        sdiff[tid][3] = dx * dx + dy * dy + dz * dz;
        scw[tid] = 0.0f;
    }
    __syncthreads();

    // ---- stage m = silu(P[row]+Q[col]+dsq*wd), packed f16 math ----
    {
        const f16x8* Pv = (const f16x8*)P;
        const f16x8* Qv = (const f16x8*)Q;
        const int kb = tid & 31;
        const int eb = tid >> 5;      // 0..7
        union { f16x8 v; __half2 h[4]; } wdu;
        wdu.v = ((const f16x8*)wdh)[kb];
        const __half2 one2 = __float2half2_rn(1.0f);
        #pragma unroll 4
        for (int i = 0; i < 8; i++) {
            const int e = eb + i * 8;
            const __half2 d2 = __float2half2_rn(sdiff[e][3]);
            union { f16x8 v; __half2 h[4]; } pu, qu, su;
            pu.v = Pv[(size_t)srow[e] * 32 + kb];
            qu.v = Qv[(size_t)scol[e] * 32 + kb];
            #pragma unroll
            for (int j = 0; j < 4; j++) {
                const __half2 s = __hfma2(wdu.h[j], d2, __hadd2(pu.h[j], qu.h[j]));
                const __half2 ex = h2exp(__hneg2(s));
                const __half2 dn = __hadd2(one2, ex);
                su.h[j] = __hmul2(s, h2rcp(dn));
            }
            Ap[kb * 64 + (e ^ (kb & 7))] = su.v;
        }
    }
    __syncthreads();

    const f16x8* Bp2v = (const f16x8*)Bp2;
    const f16x8* Bp3v = (const f16x8*)Bp3;

    // ---- GEMM2: m_ij = silu(m @ e_w2 + e_b2), M=64 x N=64 per wave ----
    f32x16 acc0[2], acc1[2];
    #pragma unroll
    for (int nt = 0; nt < 2; nt++)
        #pragma unroll
        for (int r = 0; r < 16; r++) { acc0[nt][r] = 0.0f; acc1[nt][r] = 0.0f; }

    #pragma unroll 4
    for (int kk = 0; kk < 16; kk++) {
        const int kb = kk * 2 + hh;
        const f16x8 a0 = Ap[kb * 64 + (l31 ^ (kb & 7))];
        const f16x8 a1 = Ap[kb * 64 + ((32 + l31) ^ (kb & 7))];
        #pragma unroll
        for (int nt = 0; nt < 2; nt++) {
            const f16x8 b = Bp2v[(size_t)kb * 256 + w * 64 + nt * 32 + l31];
            acc0[nt] = __builtin_amdgcn_mfma_f32_32x32x16_f16(a0, b, acc0[nt], 0, 0, 0);
            acc1[nt] = __builtin_amdgcn_mfma_f32_32x32x16_f16(a1, b, acc1[nt], 0, 0, 0);
        }
    }

    __syncthreads();   // all waves done reading m from Ap

    // silu + bias, write m_ij into Ap (A-frag layout)
    {
        _Float16* Apf = (_Float16*)Ap;
        #pragma unroll
        for (int nt = 0; nt < 2; nt++) {
            const int c = w * 64 + nt * 32 + l31;
            const float bias = eb2[c];
            const int kb2 = c >> 3;
            const int j = c & 7;
            #pragma unroll
            for (int r = 0; r < 16; r++) {
                const int e0 = (r & 3) + 8 * (r >> 2) + 4 * hh;
                Apf[(size_t)(kb2 * 64 + (e0 ^ (kb2 & 7))) * 8 + j] =
                    (_Float16)silu1(acc0[nt][r] + bias);
                Apf[(size_t)(kb2 * 64 + ((e0 + 32) ^ (kb2 & 7))) * 8 + j] =
                    (_Float16)silu1(acc1[nt][r] + bias);
            }
        }
    }
    __syncthreads();

    // ---- GEMM3: p = m_ij @ c_w1 + c_b1; cw = silu(p) . c_w2 ----
    #pragma unroll
    for (int nt = 0; nt < 2; nt++)
        #pragma unroll
        for (int r = 0; r < 16; r++) { acc0[nt][r] = 0.0f; acc1[nt][r] = 0.0f; }

    #pragma unroll 4
    for (int kk = 0; kk < 16; kk++) {
        const int kb = kk * 2 + hh;
        const f16x8 a0 = Ap[kb * 64 + (l31 ^ (kb & 7))];
        const f16x8 a1 = Ap[kb * 64 + ((32 + l31) ^ (kb & 7))];
        #pragma unroll
        for (int nt = 0; nt < 2; nt++) {
            const f16x8 b = Bp3v[(size_t)kb * 256 + w * 64 + nt * 32 + l31];
            acc0[nt] = __builtin_amdgcn_mfma_f32_32x32x16_f16(a0, b, acc0[nt], 0, 0, 0);
            acc1[nt] = __builtin_amdgcn_mfma_f32_32x32x16_f16(a1, b, acc1[nt], 0, 0, 0);
        }
    }

    {
        float p0[16], p1[16];
        #pragma unroll
        for (int r = 0; r < 16; r++) { p0[r] = 0.0f; p1[r] = 0.0f; }
        #pragma unroll
        for (int nt = 0; nt < 2; nt++) {
            const int c = w * 64 + nt * 32 + l31;
            const float bias = cb1[c];
            const float cwv = cw2[c];
            #pragma unroll
            for (int r = 0; r < 16; r++) {
                p0[r] += silu1(acc0[nt][r] + bias) * cwv;
                p1[r] += silu1(acc1[nt][r] + bias) * cwv;
            }
        }
        #pragma unroll
        for (int m = 1; m < 32; m <<= 1) {
            #pragma unroll
            for (int r = 0; r < 16; r++) {
                p0[r] += __shfl_xor(p0[r], m);
                p1[r] += __shfl_xor(p1[r], m);
            }
        }
        if (l31 == 0) {
            #pragma unroll
            for (int r = 0; r < 16; r++) {
                const int e0 = (r & 3) + 8 * (r >> 2) + 4 * hh;
                atomicAdd(&scw[e0], p0[r]);
                atomicAdd(&scw[e0 + 32], p1[r]);
            }
        }
    }
    __syncthreads();   // scw + m_ij complete

    // ---- msg segmented reduction: thread owns channel tid ----
    {
        const _Float16* Apf = (const _Float16*)Ap;
        const int c = tid;
        const int kb = c >> 3;
        const int j = c & 7;
        float accm = 0.0f;
        #pragma unroll 4
        for (int e = 0; e < TE; e++) {
            accm += (float)Apf[(size_t)(kb * 64 + (e ^ (kb & 7))) * 8 + j];
            const int col = scol[e];
            const int nxt = (e == TE - 1) ? -1 : scol[e + 1];
            if (col != nxt) {
                atomicAdd(msg + (size_t)col * H + c, accm);
                accm = 0.0f;
            }
        }
    }

    // ---- coord segmented reduction ----
    if (tid < 3) {
        const int d = tid;
        float accc = 0.0f;
        for (int e = 0; e < TE; e++) {
            accc += scw[e] * sdiff[e][d];
            const int col = scol[e];
            const int nxt = (e == TE - 1) ? -1 : scol[e + 1];
            if (col != nxt) {
                atomicAdd(xout + (size_t)col * 3 + d, accc);
                accc = 0.0f;
            }
        }
    }
}

// ---------------- node kernel (MFMA): 32 nodes/block, 256 threads -----------
__global__ __launch_bounds__(256) void k_node(
    const float* __restrict__ h, const float* __restrict__ msg,
    const _Float16* __restrict__ BpA, const float* __restrict__ nb1,
    const _Float16* __restrict__ BpB, const float* __restrict__ nb2,
    const float* __restrict__ lng, const float* __restrict__ lnb,
    float* __restrict__ hout) {
    __shared__ f16x8 ApA[64 * 32];
    __shared__ f16x8 Tp[32 * 32];
    __shared__ float s1[32];
    __shared__ float s2[32];
    const int tid = threadIdx.x;
    const int l = tid & 63;
    const int w = tid >> 6;
    const int l31 = l & 31;
    const int hh = l >> 5;
    const int n0 = blockIdx.x * 32;

    if (tid < 32) { s1[tid] = 0.0f; s2[tid] = 0.0f; }

    {
        const int kb = tid & 31;
        const int eb = tid >> 5;
        #pragma unroll
        for (int i = 0; i < 4; i++) {
            const int e = eb + i * 8;
            #pragma unroll
            for (int half = 0; half < 2; half++) {
                const float* A = half ? msg : h;
                const int kb2 = kb + half * 32;
                const float4 v0 = *(const float4*)(A + (size_t)(n0 + e) * H + kb * 8);
                const float4 v1 = *(const float4*)(A + (size_t)(n0 + e) * H + kb * 8 + 4);
                f16x8 pk;
                pk[0] = (_Float16)v0.x; pk[1] = (_Float16)v0.y;
                pk[2] = (_Float16)v0.z; pk[3] = (_Float16)v0.w;
                pk[4] = (_Float16)v1.x; pk[5] = (_Float16)v1.y;
                pk[6] = (_Float16)v1.z; pk[7] = (_Float16)v1.w;
                ApA[kb2 * 32 + (e ^ (kb2 & 7))] = pk;
            }
        }
    }
    __syncthreads();

    const f16x8* BvA = (const f16x8*)BpA;
    const f16x8* BvB = (const f16x8*)BpB;

    f32x16 acc[2];
    #pragma unroll
    for (int nt = 0; nt < 2; nt++)
        #pragma unroll
        for (int r = 0; r < 16; r++) acc[nt][r] = 0.0f;

    #pragma unroll 4
    for (int kk = 0; kk < 32; kk++) {
        const int kb = kk * 2 + hh;
        const f16x8 a = ApA[kb * 32 + (l31 ^ (kb & 7))];
        #pragma unroll
        for (int nt = 0; nt < 2; nt++) {
            const f16x8 b = BvA[(size_t)kb * 256 + w * 64 + nt * 32 + l31];
            acc[nt] = __builtin_amdgcn_mfma_f32_32x32x16_f16(a, b, acc[nt], 0, 0, 0);
        }
    }

    {
        _Float16* Tpf = (_Float16*)Tp;
        #pragma unroll
        for (int nt = 0; nt < 2; nt++) {
            const int col = w * 64 + nt * 32 + l31;
            const float bias = nb1[col];
            const int kb2 = col >> 3;
            const int j = col & 7;
            #pragma unroll
            for (int r = 0; r < 16; r++) {
                const int e = (r & 3) + 8 * (r >> 2) + 4 * hh;
                Tpf[(size_t)(kb2 * 32 + (e ^ (kb2 & 7))) * 8 + j] =
                    (_Float16)silu1(acc[nt][r] + bias);
            }
        }
    }
    __syncthreads();

    f32x16 y[2];
    #pragma unroll
    for (int nt = 0; nt < 2; nt++)
        #pragma unroll
        for (int r = 0; r < 16; r++) y[nt][r] = 0.0f;

    #pragma unroll 4
    for (int kk = 0; kk < 16; kk++) {
        const int kb = kk * 2 + hh;
        const f16x8 a = Tp[kb * 32 + (l31 ^ (kb & 7))];
        #pragma unroll
        for (int nt = 0; nt < 2; nt++) {
            const f16x8 b = BvB[(size_t)kb * 256 + w * 64 + nt * 32 + l31];
            y[nt] = __builtin_amdgcn_mfma_f32_32x32x16_f16(a, b, y[nt], 0, 0, 0);
        }
    }

    float t1[16], t2[16];
    #pragma unroll
    for (int r = 0; r < 16; r++) { t1[r] = 0.0f; t2[r] = 0.0f; }
    #pragma unroll
    for (int nt = 0; nt < 2; nt++) {
        const int col = w * 64 + nt * 32 + l31;
        const float bias = nb2[col];
        #pragma unroll
        for (int r = 0; r < 16; r++) {
            const int node = n0 + (r & 3) + 8 * (r >> 2) + 4 * hh;
            const float v = y[nt][r] + bias + h[(size_t)node * H + col];
            y[nt][r] = v;
            t1[r] += v;
            t2[r] += v * v;
        }
    }
    #pragma unroll
    for (int m = 1; m < 32; m <<= 1) {
        #pragma unroll
        for (int r = 0; r < 16; r++) {
            t1[r] += __shfl_xor(t1[r], m);
            t2[r] += __shfl_xor(t2[r], m);
        }
    }
    if (l31 == 0) {
        #pragma unroll
        for (int r = 0; r < 16; r++) {
            const int row = (r & 3) + 8 * (r >> 2) + 4 * hh;
            atomicAdd(&s1[row], t1[r]);
            atomicAdd(&s2[row], t2[r]);
        }
    }
    __syncthreads();

    #pragma unroll
    for (int nt = 0; nt < 2; nt++) {
        const int col = w * 64 + nt * 32 + l31;
        const float g = lng[col];
        const float bb = lnb[col];
        #pragma unroll
        for (int r = 0; r < 16; r++) {
            const int row = (r & 3) + 8 * (r >> 2) + 4 * hh;
            const int node = n0 + row;
            const float mu = s1[row] * (1.0f / H);
            const float var = s2[row] * (1.0f / H) - mu * mu;
            const float rs = rsqrtf(var + LN_EPS);
            hout[(size_t)node * H + col] = (y[nt][r] - mu) * rs * g + bb;
        }
    }
}

extern "C" void kernel_launch(void* const* d_in, const int* in_sizes, int n_in,
                              void* d_out, int out_size, void* d_ws, size_t ws_size,
                              hipStream_t stream) {
    const float* h   = (const float*)d_in[0];
    const float* x   = (const float*)d_in[1];
    const int*   ei  = (const int*)d_in[2];
    const float* ew1 = (const float*)d_in[3];
    const float* eb1 = (const float*)d_in[4];
    const float* ew2 = (const float*)d_in[5];
    const float* eb2 = (const float*)d_in[6];
    const float* cw1 = (const float*)d_in[7];
    const float* cb1 = (const float*)d_in[8];
    const float* cw2 = (const float*)d_in[9];
    const float* nw1 = (const float*)d_in[10];
    const float* nb1 = (const float*)d_in[11];
    const float* nw2 = (const float*)d_in[12];
    const float* nb2 = (const float*)d_in[13];
    const float* lng = (const float*)d_in[14];
    const float* lnb = (const float*)d_in[15];

    float* hout = (float*)d_out;
    float* xout = hout + (size_t)NN * H;

    float* msg = (float*)d_ws;                              // NN*H f32
    int* bins = (int*)(msg + (size_t)NN * H);               // NN (memset w/ msg)
    _Float16* P   = (_Float16*)(bins + NN);                 // NN*H f16
    _Float16* Qq  = P + (size_t)NN * H;                     // NN*H f16
    _Float16* Bp2 = Qq + (size_t)NN * H;                    // 256*256
    _Float16* Bp3 = Bp2 + 256 * 256;
    _Float16* BpB = Bp3 + 256 * 256;
    _Float16* BpA = BpB + 256 * 256;                        // 512*256
    _Float16* Bp1 = BpA + 512 * 256;                        // 256*512
    _Float16* wdh = Bp1 + 256 * 512;                        // 256
    int* cursor = (int*)(wdh + 256);
    int* perm   = cursor + NN;

    hipMemsetAsync(d_ws, 0, (size_t)NN * H * 4 + NN * 4, stream);
    k_misc<<<2126, 256, 0, stream>>>(ei, bins, x, xout, ew2, cw1, nw2, nw1, ew1,
                                     Bp2, Bp3, BpB, BpA, Bp1, wdh);
    k_scan<<<1, 1024, 0, stream>>>(bins, cursor);
    k_scatter<<<(NE + 255) / 256, 256, 0, stream>>>(ei, cursor, perm);
    k_pre<<<NN / 32, 256, 0, stream>>>(h, Bp1, eb1, P, Qq);
    k_edge<<<NE / TE, 256, 0, stream>>>(x, ei, perm, P, Qq, wdh, Bp2, eb2,
                                        Bp3, cb1, cw2, msg, xout);
    k_node<<<NN / 32, 256, 0, stream>>>(h, msg, BpA, nb1, BpB, nb2,
                                        lng, lnb, hout);
}

// Round 10
// 371.994 us; speedup vs baseline: 4.5266x; 1.0605x over previous
//
#include <hip/hip_runtime.h>
#include <hip/hip_fp16.h>
#include <math.h>

#define NN 20000
#define NE 320000
#define H 256
#define LN_EPS 1e-5f
#define TE 64   // edges per block (edge kernel)

typedef _Float16 f16x8 __attribute__((ext_vector_type(8)));
typedef float f32x16 __attribute__((ext_vector_type(16)));

__device__ __forceinline__ float silu1(float v) {
    return __fdividef(v, 1.0f + __expf(-v));
}

__device__ __forceinline__ __half2 silu2(const __half2 s) {
    const __half2 one2 = __float2half2_rn(1.0f);
    return __hmul2(s, h2rcp(__hadd2(one2, h2exp(__hneg2(s)))));
}

// ---------------- misc kernel (NO pre zone — Bp1 consumer must be a
// separate launch: intra-kernel producer/consumer across blocks races) ------
// zones: [0,1250) hist, [1250,1485) xcopy, [1485,2125) pack, 2125 wdist
__global__ __launch_bounds__(256) void k_misc(
    const int* __restrict__ ei, int* __restrict__ bins,
    const float* __restrict__ x, float* __restrict__ xout,
    const float* __restrict__ ew2, const float* __restrict__ cw1,
    const float* __restrict__ nw2, const float* __restrict__ nw1,
    const float* __restrict__ ew1,
    _Float16* __restrict__ Bp2, _Float16* __restrict__ Bp3,
    _Float16* __restrict__ BpB, _Float16* __restrict__ BpA,
    _Float16* __restrict__ Bp1, _Float16* __restrict__ wdh) {
    const int b = blockIdx.x;
    const int tid = threadIdx.x;
    if (b < 1250) {                           // hist
        atomicAdd(&bins[ei[NE + b * 256 + tid]], 1);
    } else if (b < 1485) {                    // xcopy
        const int i = (b - 1250) * 256 + tid;
        if (i < NN * 3) xout[i] = x[i];
    } else if (b < 2125) {                    // weight pack
        const int pb = b - 1485;
        const int which = pb >> 7;
        const int bx = pb & 127;
        const int n = tid;
        if (which < 3) {                      // K=256, N=256
            if (bx >= 64) return;
            const float* W = (which == 0) ? ew2 : (which == 1) ? cw1 : nw2;
            _Float16* Bp = (which == 0) ? Bp2 : (which == 1) ? Bp3 : BpB;
            #pragma unroll
            for (int kr = 0; kr < 4; kr++) {
                const int k = bx * 4 + kr;
                Bp[((size_t)(k >> 3) * 256 + n) * 8 + (k & 7)] =
                    (_Float16)W[(size_t)k * 256 + n];
            }
        } else if (which == 3) {              // nw1: K=512, N=256
            #pragma unroll
            for (int kr = 0; kr < 4; kr++) {
                const int k = bx * 4 + kr;
                BpA[((size_t)(k >> 3) * 256 + n) * 8 + (k & 7)] =
                    (_Float16)nw1[(size_t)k * 256 + n];
            }
        } else {                              // ew1 combined: K=256, N=512
            if (bx >= 64) return;
            #pragma unroll
            for (int kr = 0; kr < 4; kr++) {
                const int k = bx * 4 + kr;
                Bp1[((size_t)(k >> 3) * 512 + n) * 8 + (k & 7)] =
                    (_Float16)ew1[(size_t)k * 256 + n];
                Bp1[((size_t)(k >> 3) * 512 + 256 + n) * 8 + (k & 7)] =
                    (_Float16)ew1[(size_t)(256 + k) * 256 + n];
            }
        }
    } else {                                  // wdist row of ew1 -> f16
        wdh[tid] = (_Float16)ew1[(size_t)512 * H + tid];
    }
}

// ---------------- pre (MFMA): [P|Q] = h @ [W_top|W_bot] (+b1 on P) ----------
// MUST launch after k_misc (consumes Bp1).
__global__ __launch_bounds__(256) void k_pre(const float* __restrict__ h,
                                             const _Float16* __restrict__ Bp1,
                                             const float* __restrict__ eb1,
                                             _Float16* __restrict__ P,
                                             _Float16* __restrict__ Q) {
    __shared__ f16x8 Ap[32 * 32];
    const int tid = threadIdx.x;
    const int l = tid & 63;
    const int w = tid >> 6;
    const int l31 = l & 31;
    const int hh = l >> 5;
    const int n0 = blockIdx.x * 32;

    {
        const int kb = tid & 31;
        const int eb = tid >> 5;
        #pragma unroll
        for (int i = 0; i < 4; i++) {
            const int e = eb + i * 8;
            const float4 v0 = *(const float4*)(h + (size_t)(n0 + e) * H + kb * 8);
            const float4 v1 = *(const float4*)(h + (size_t)(n0 + e) * H + kb * 8 + 4);
            f16x8 pk;
            pk[0] = (_Float16)v0.x; pk[1] = (_Float16)v0.y;
            pk[2] = (_Float16)v0.z; pk[3] = (_Float16)v0.w;
            pk[4] = (_Float16)v1.x; pk[5] = (_Float16)v1.y;
            pk[6] = (_Float16)v1.z; pk[7] = (_Float16)v1.w;
            Ap[kb * 32 + (e ^ (kb & 7))] = pk;
        }
    }
    __syncthreads();

    const f16x8* Bv = (const f16x8*)Bp1;
    f32x16 acc[4];
    #pragma unroll
    for (int nt = 0; nt < 4; nt++)
        #pragma unroll
        for (int r = 0; r < 16; r++) acc[nt][r] = 0.0f;

    #pragma unroll 4
    for (int kk = 0; kk < 16; kk++) {
        const int kb = kk * 2 + hh;
        const f16x8 a = Ap[kb * 32 + (l31 ^ (kb & 7))];
        #pragma unroll
        for (int nt = 0; nt < 4; nt++) {
            const f16x8 bfr = Bv[(size_t)kb * 512 + w * 128 + nt * 32 + l31];
            acc[nt] = __builtin_amdgcn_mfma_f32_32x32x16_f16(a, bfr, acc[nt], 0, 0, 0);
        }
    }

    #pragma unroll
    for (int nt = 0; nt < 4; nt++) {
        const int col = w * 128 + nt * 32 + l31;
        const float bias = (col < 256) ? eb1[col] : 0.0f;
        #pragma unroll
        for (int r = 0; r < 16; r++) {
            const int node = n0 + (r & 3) + 8 * (r >> 2) + 4 * hh;
            const float v = acc[nt][r] + bias;
            if (col < 256) P[(size_t)node * H + col] = (_Float16)v;
            else           Q[(size_t)node * H + col - 256] = (_Float16)v;
        }
    }
}

// shuffle-based exclusive scan of 20000 bins, one block of 1024 threads
__global__ __launch_bounds__(1024) void k_scan(const int* __restrict__ bins,
                                               int* __restrict__ cursor) {
    __shared__ int wsum[16];
    __shared__ int wbase[16];
    const int tid = threadIdx.x;
    const int lane = tid & 63;
    const int wid = tid >> 6;
    const int base = tid * 20;
    int loc[20];
    int sum = 0;
    #pragma unroll
    for (int j = 0; j < 20; j++) {
        const int idx = base + j;
        const int v = (idx < NN) ? bins[idx] : 0;
        loc[j] = sum;
        sum += v;
    }
    int inc = sum;
    #pragma unroll
    for (int off = 1; off < 64; off <<= 1) {
        const int t = __shfl_up(inc, off);
        if (lane >= off) inc += t;
    }
    if (lane == 63) wsum[wid] = inc;
    __syncthreads();
    if (tid < 64) {
        int v = (tid < 16) ? wsum[tid] : 0;
        int inc2 = v;
        #pragma unroll
        for (int off = 1; off < 16; off <<= 1) {
            const int t = __shfl_up(inc2, off);
            if (lane >= off) inc2 += t;
        }
        if (tid < 16) wbase[tid] = inc2 - v;
    }
    __syncthreads();
    const int excl = wbase[wid] + inc - sum;
    #pragma unroll
    for (int j = 0; j < 20; j++) {
        const int idx = base + j;
        if (idx < NN) cursor[idx] = excl + loc[j];
    }
}

__global__ void k_scatter(const int* __restrict__ ei, int* __restrict__ cursor,
                          int* __restrict__ perm) {
    const int e = blockIdx.x * blockDim.x + threadIdx.x;
    if (e < NE) {
        const int c = ei[NE + e];
        const int pos = atomicAdd(&cursor[c], 1);
        perm[pos] = e;
    }
}

// ---------------- edge kernel: 64 edges/block, 256 threads, 4 waves ---------
// Wave w: M=64 (edges, two 32-row tiles a0/a1) x N=64 (channels w*64..+63).
__global__ __launch_bounds__(256, 4) void k_edge(
    const float* __restrict__ x, const int* __restrict__ ei,
    const int* __restrict__ perm,
    const _Float16* __restrict__ P, const _Float16* __restrict__ Q,
    const _Float16* __restrict__ wdh,
    const _Float16* __restrict__ Bp2, const float* __restrict__ eb2,
    const _Float16* __restrict__ Bp3, const float* __restrict__ cb1,
    const float* __restrict__ cw2,
    float* __restrict__ msg, float* __restrict__ xout) {
    __shared__ f16x8 Ap[32 * 64];     // 32 KB: m, then m_ij (A-frag layout)
    __shared__ float sdiff[TE][4];
    __shared__ int srow[TE];
    __shared__ int scol[TE];
    __shared__ float scw[TE];

    const int tid = threadIdx.x;      // 0..255
    const int e0blk = blockIdx.x * TE;
    const int l = tid & 63;
    const int w = tid >> 6;           // channel quarter: w*64
    const int l31 = l & 31;
    const int hh = l >> 5;

    if (tid < TE) {
        const int e = perm[e0blk + tid];
        const int r = ei[e];
        const int c = ei[NE + e];
        const float dx = x[r * 3 + 0] - x[c * 3 + 0];
        const float dy = x[r * 3 + 1] - x[c * 3 + 1];
        const float dz = x[r * 3 + 2] - x[c * 3 + 2];
        srow[tid] = r; scol[tid] = c;
        sdiff[tid][0] = dx; sdiff[tid][1] = dy; sdiff[tid][2] = dz;
        sdiff[tid][3] = dx * dx + dy * dy + dz * dz;
        scw[tid] = 0.0f;
    }
    __syncthreads();

    // ---- stage m = silu(P[row]+Q[col]+dsq*wd), packed f16 math ----
    {
        const f16x8* Pv = (const f16x8*)P;
        const f16x8* Qv = (const f16x8*)Q;
        const int kb = tid & 31;
        const int eb = tid >> 5;      // 0..7
        union { f16x8 v; __half2 h[4]; } wdu;
        wdu.v = ((const f16x8*)wdh)[kb];
        #pragma unroll 4
        for (int i = 0; i < 8; i++) {
            const int e = eb + i * 8;
            const __half2 d2 = __float2half2_rn(sdiff[e][3]);
            union { f16x8 v; __half2 h[4]; } pu, qu, su;
            pu.v = Pv[(size_t)srow[e] * 32 + kb];
            qu.v = Qv[(size_t)scol[e] * 32 + kb];
            #pragma unroll
            for (int j = 0; j < 4; j++) {
                const __half2 s = __hfma2(wdu.h[j], d2, __hadd2(pu.h[j], qu.h[j]));
                su.h[j] = silu2(s);
            }
            Ap[kb * 64 + (e ^ (kb & 7))] = su.v;
        }
    }
    __syncthreads();

    const f16x8* Bp2v = (const f16x8*)Bp2;
    const f16x8* Bp3v = (const f16x8*)Bp3;

    // ---- GEMM2: m_ij = silu(m @ e_w2 + e_b2), M=64 x N=64 per wave ----
    f32x16 acc0[2], acc1[2];
    #pragma unroll
    for (int nt = 0; nt < 2; nt++)
        #pragma unroll
        for (int r = 0; r < 16; r++) { acc0[nt][r] = 0.0f; acc1[nt][r] = 0.0f; }

    #pragma unroll 4
    for (int kk = 0; kk < 16; kk++) {
        const int kb = kk * 2 + hh;
        const f16x8 a0 = Ap[kb * 64 + (l31 ^ (kb & 7))];
        const f16x8 a1 = Ap[kb * 64 + ((32 + l31) ^ (kb & 7))];
        #pragma unroll
        for (int nt = 0; nt < 2; nt++) {
            const f16x8 b = Bp2v[(size_t)kb * 256 + w * 64 + nt * 32 + l31];
            acc0[nt] = __builtin_amdgcn_mfma_f32_32x32x16_f16(a0, b, acc0[nt], 0, 0, 0);
            acc1[nt] = __builtin_amdgcn_mfma_f32_32x32x16_f16(a1, b, acc1[nt], 0, 0, 0);
        }
    }

    __syncthreads();   // all waves done reading m from Ap

    // silu + bias (packed), write m_ij into Ap (A-frag layout)
    {
        __half* Aph = (__half*)Ap;
        #pragma unroll
        for (int nt = 0; nt < 2; nt++) {
            const int c = w * 64 + nt * 32 + l31;
            const float bias = eb2[c];
            const int kb2 = c >> 3;
            const int j = c & 7;
            #pragma unroll
            for (int r = 0; r < 16; r++) {
                const __half2 o = silu2(__floats2half2_rn(acc0[nt][r] + bias,
                                                          acc1[nt][r] + bias));
                const int e0 = (r & 3) + 8 * (r >> 2) + 4 * hh;
                Aph[(size_t)(kb2 * 64 + (e0 ^ (kb2 & 7))) * 8 + j] = __low2half(o);
                Aph[(size_t)(kb2 * 64 + ((e0 + 32) ^ (kb2 & 7))) * 8 + j] = __high2half(o);
            }
        }
    }
    __syncthreads();

    // ---- GEMM3: p = m_ij @ c_w1 + c_b1; cw = silu(p) . c_w2 ----
    #pragma unroll
    for (int nt = 0; nt < 2; nt++)
        #pragma unroll
        for (int r = 0; r < 16; r++) { acc0[nt][r] = 0.0f; acc1[nt][r] = 0.0f; }

    #pragma unroll 4
    for (int kk = 0; kk < 16; kk++) {
        const int kb = kk * 2 + hh;
        const f16x8 a0 = Ap[kb * 64 + (l31 ^ (kb & 7))];
        const f16x8 a1 = Ap[kb * 64 + ((32 + l31) ^ (kb & 7))];
        #pragma unroll
        for (int nt = 0; nt < 2; nt++) {
            const f16x8 b = Bp3v[(size_t)kb * 256 + w * 64 + nt * 32 + l31];
            acc0[nt] = __builtin_amdgcn_mfma_f32_32x32x16_f16(a0, b, acc0[nt], 0, 0, 0);
            acc1[nt] = __builtin_amdgcn_mfma_f32_32x32x16_f16(a1, b, acc1[nt], 0, 0, 0);
        }
    }

    {
        __half2 p[16];
        #pragma unroll
        for (int r = 0; r < 16; r++) p[r] = __float2half2_rn(0.0f);
        #pragma unroll
        for (int nt = 0; nt < 2; nt++) {
            const int c = w * 64 + nt * 32 + l31;
            const float bias = cb1[c];
            const __half2 cwv = __float2half2_rn(cw2[c]);
            #pragma unroll
            for (int r = 0; r < 16; r++) {
                const __half2 s = __floats2half2_rn(acc0[nt][r] + bias,
                                                    acc1[nt][r] + bias);
                p[r] = __hfma2(silu2(s), cwv, p[r]);
            }
        }
        #pragma unroll
        for (int m = 1; m < 32; m <<= 1) {
            #pragma unroll
            for (int r = 0; r < 16; r++) {
                union { __half2 h; int i; } u, v;
                u.h = p[r];
                v.i = __shfl_xor(u.i, m);
                p[r] = __hadd2(u.h, v.h);
            }
        }
        if (l31 == 0) {
            #pragma unroll
            for (int r = 0; r < 16; r++) {
                const int e0 = (r & 3) + 8 * (r >> 2) + 4 * hh;
                atomicAdd(&scw[e0], __low2float(p[r]));
                atomicAdd(&scw[e0 + 32], __high2float(p[r]));
            }
        }
    }
    __syncthreads();   // scw + m_ij complete

    // ---- msg segmented reduction: thread owns channel tid (f32 atomics) ----
    {
        const _Float16* Apf = (const _Float16*)Ap;
        const int c = tid;
        const int kb = c >> 3;
        const int j = c & 7;
        float accm = 0.0f;
        #pragma unroll 4
        for (int e = 0; e < TE; e++) {
            accm += (float)Apf[(size_t)(kb * 64 + (e ^ (kb & 7))) * 8 + j];
            const int col = scol[e];
            const int nxt = (e == TE - 1) ? -1 : scol[e + 1];
            if (col != nxt) {
                atomicAdd(msg + (size_t)col * H + c, accm);
                accm = 0.0f;
            }
        }
    }

    // ---- coord segmented reduction ----
    if (tid < 3) {
        const int d = tid;
        float accc = 0.0f;
        for (int e = 0; e < TE; e++) {
            accc += scw[e] * sdiff[e][d];
            const int col = scol[e];
            const int nxt = (e == TE - 1) ? -1 : scol[e + 1];
            if (col != nxt) {
                atomicAdd(xout + (size_t)col * 3 + d, accc);
                accc = 0.0f;
            }
        }
    }
}

// ---------------- node kernel (MFMA): 32 nodes/block, 256 threads -----------
__global__ __launch_bounds__(256) void k_node(
    const float* __restrict__ h, const float* __restrict__ msg,
    const _Float16* __restrict__ BpA, const float* __restrict__ nb1,
    const _Float16* __restrict__ BpB, const float* __restrict__ nb2,
    const float* __restrict__ lng, const float* __restrict__ lnb,
    float* __restrict__ hout) {
    __shared__ f16x8 ApA[64 * 32];
    __shared__ f16x8 Tp[32 * 32];
    __shared__ float s1[32];
    __shared__ float s2[32];
    const int tid = threadIdx.x;
    const int l = tid & 63;
    const int w = tid >> 6;
    const int l31 = l & 31;
    const int hh = l >> 5;
    const int n0 = blockIdx.x * 32;

    if (tid < 32) { s1[tid] = 0.0f; s2[tid] = 0.0f; }

    {
        const int kb = tid & 31;
        const int eb = tid >> 5;
        #pragma unroll
        for (int i = 0; i < 4; i++) {
            const int e = eb + i * 8;
            #pragma unroll
            for (int half = 0; half < 2; half++) {
                const float* A = half ? msg : h;
                const int kb2 = kb + half * 32;
                const float4 v0 = *(const float4*)(A + (size_t)(n0 + e) * H + kb * 8);
                const float4 v1 = *(const float4*)(A + (size_t)(n0 + e) * H + kb * 8 + 4);
                f16x8 pk;
                pk[0] = (_Float16)v0.x; pk[1] = (_Float16)v0.y;
                pk[2] = (_Float16)v0.z; pk[3] = (_Float16)v0.w;
                pk[4] = (_Float16)v1.x; pk[5] = (_Float16)v1.y;
                pk[6] = (_Float16)v1.z; pk[7] = (_Float16)v1.w;
                ApA[kb2 * 32 + (e ^ (kb2 & 7))] = pk;
            }
        }
    }
    __syncthreads();

    const f16x8* BvA = (const f16x8*)BpA;
    const f16x8* BvB = (const f16x8*)BpB;

    f32x16 acc[2];
    #pragma unroll
    for (int nt = 0; nt < 2; nt++)
        #pragma unroll
        for (int r = 0; r < 16; r++) acc[nt][r] = 0.0f;

    #pragma unroll 4
    for (int kk = 0; kk < 32; kk++) {
        const int kb = kk * 2 + hh;
        const f16x8 a = ApA[kb * 32 + (l31 ^ (kb & 7))];
        #pragma unroll
        for (int nt = 0; nt < 2; nt++) {
            const f16x8 b = BvA[(size_t)kb * 256 + w * 64 + nt * 32 + l31];
            acc[nt] = __builtin_amdgcn_mfma_f32_32x32x16_f16(a, b, acc[nt], 0, 0, 0);
        }
    }

    {
        _Float16* Tpf = (_Float16*)Tp;
        #pragma unroll
        for (int nt = 0; nt < 2; nt++) {
            const int col = w * 64 + nt * 32 + l31;
            const float bias = nb1[col];
            const int kb2 = col >> 3;
            const int j = col & 7;
            #pragma unroll
            for (int r = 0; r < 16; r++) {
                const int e = (r & 3) + 8 * (r >> 2) + 4 * hh;
                Tpf[(size_t)(kb2 * 32 + (e ^ (kb2 & 7))) * 8 + j] =
                    (_Float16)silu1(acc[nt][r] + bias);
            }
        }
    }
    __syncthreads();

    f32x16 y[2];
    #pragma unroll
    for (int nt = 0; nt < 2; nt++)
        #pragma unroll
        for (int r = 0; r < 16; r++) y[nt][r] = 0.0f;

    #pragma unroll 4
    for (int kk = 0; kk < 16; kk++) {
        const int kb = kk * 2 + hh;
        const f16x8 a = Tp[kb * 32 + (l31 ^ (kb & 7))];
        #pragma unroll
        for (int nt = 0; nt < 2; nt++) {
            const f16x8 b = BvB[(size_t)kb * 256 + w * 64 + nt * 32 + l31];
            y[nt] = __builtin_amdgcn_mfma_f32_32x32x16_f16(a, b, y[nt], 0, 0, 0);
        }
    }

    float t1[16], t2[16];
    #pragma unroll
    for (int r = 0; r < 16; r++) { t1[r] = 0.0f; t2[r] = 0.0f; }
    #pragma unroll
    for (int nt = 0; nt < 2; nt++) {
        const int col = w * 64 + nt * 32 + l31;
        const float bias = nb2[col];
        #pragma unroll
        for (int r = 0; r < 16; r++) {
            const int node = n0 + (r & 3) + 8 * (r >> 2) + 4 * hh;
            const float v = y[nt][r] + bias + h[(size_t)node * H + col];
            y[nt][r] = v;
            t1[r] += v;
            t2[r] += v * v;
        }
    }
    #pragma unroll
    for (int m = 1; m < 32; m <<= 1) {
        #pragma unroll
        for (int r = 0; r < 16; r++) {
            t1[r] += __shfl_xor(t1[r], m);
            t2[r] += __shfl_xor(t2[r], m);
        }
    }
    if (l31 == 0) {
        #pragma unroll
        for (int r = 0; r < 16; r++) {
            const int row = (r & 3) + 8 * (r >> 2) + 4 * hh;
            atomicAdd(&s1[row], t1[r]);
            atomicAdd(&s2[row], t2[r]);
        }
    }
    __syncthreads();

    #pragma unroll
    for (int nt = 0; nt < 2; nt++) {
        const int col = w * 64 + nt * 32 + l31;
        const float g = lng[col];
        const float bb = lnb[col];
        #pragma unroll
        for (int r = 0; r < 16; r++) {
            const int row = (r & 3) + 8 * (r >> 2) + 4 * hh;
            const int node = n0 + row;
            const float mu = s1[row] * (1.0f / H);
            const float var = s2[row] * (1.0f / H) - mu * mu;
            const float rs = rsqrtf(var + LN_EPS);
            hout[(size_t)node * H + col] = (y[nt][r] - mu) * rs * g + bb;
        }
    }
}

extern "C" void kernel_launch(void* const* d_in, const int* in_sizes, int n_in,
                              void* d_out, int out_size, void* d_ws, size_t ws_size,
                              hipStream_t stream) {
    const float* h   = (const float*)d_in[0];
    const float* x   = (const float*)d_in[1];
    const int*   ei  = (const int*)d_in[2];
    const float* ew1 = (const float*)d_in[3];
    const float* eb1 = (const float*)d_in[4];
    const float* ew2 = (const float*)d_in[5];
    const float* eb2 = (const float*)d_in[6];
    const float* cw1 = (const float*)d_in[7];
    const float* cb1 = (const float*)d_in[8];
    const float* cw2 = (const float*)d_in[9];
    const float* nw1 = (const float*)d_in[10];
    const float* nb1 = (const float*)d_in[11];
    const float* nw2 = (const float*)d_in[12];
    const float* nb2 = (const float*)d_in[13];
    const float* lng = (const float*)d_in[14];
    const float* lnb = (const float*)d_in[15];

    float* hout = (float*)d_out;
    float* xout = hout + (size_t)NN * H;

    float* msg = (float*)d_ws;                              // NN*H f32
    int* bins = (int*)(msg + (size_t)NN * H);               // NN (memset w/ msg)
    _Float16* P   = (_Float16*)(bins + NN);                 // NN*H f16
    _Float16* Qq  = P + (size_t)NN * H;                     // NN*H f16
    _Float16* Bp2 = Qq + (size_t)NN * H;                    // 256*256
    _Float16* Bp3 = Bp2 + 256 * 256;
    _Float16* BpB = Bp3 + 256 * 256;
    _Float16* BpA = BpB + 256 * 256;                        // 512*256
    _Float16* Bp1 = BpA + 512 * 256;                        // 256*512
    _Float16* wdh = Bp1 + 256 * 512;                        // 256
    int* cursor = (int*)(wdh + 256);
    int* perm   = cursor + NN;

    (void)hipMemsetAsync(d_ws, 0, (size_t)NN * H * 4 + NN * 4, stream);
    k_misc<<<2126, 256, 0, stream>>>(ei, bins, x, xout, ew2, cw1, nw2, nw1, ew1,
                                     Bp2, Bp3, BpB, BpA, Bp1, wdh);
    k_pre<<<NN / 32, 256, 0, stream>>>(h, Bp1, eb1, P, Qq);
    k_scan<<<1, 1024, 0, stream>>>(bins, cursor);
    k_scatter<<<(NE + 255) / 256, 256, 0, stream>>>(ei, cursor, perm);
    k_edge<<<NE / TE, 256, 0, stream>>>(x, ei, perm, P, Qq, wdh, Bp2, eb2,
                                        Bp3, cb1, cw2, msg, xout);
    k_node<<<NN / 32, 256, 0, stream>>>(h, msg, BpA, nb1, BpB, nb2,
                                        lng, lnb, hout);
}